// Round 1
// 1046.049 us; speedup vs baseline: 1.2348x; 1.2348x over previous
//
#include <hip/hip_runtime.h>
#include <hip/hip_bf16.h>
#include <stdint.h>

#define N 4096
#define LSTEPS 128
#define KSEL 16
#define NACT 3968
#define NIN 128

typedef __hip_bfloat16 bf16;
typedef __attribute__((ext_vector_type(8))) short short8;
typedef __attribute__((ext_vector_type(4))) float floatx4;

static __device__ __forceinline__ bf16 f2bf(float x) { return __float2bfloat16(x); }
static __device__ __forceinline__ float us2f(ushort u) { return __uint_as_float(((unsigned)u) << 16); }
static __device__ __forceinline__ ushort f2us(float x) { return __bfloat16_as_ushort(__float2bfloat16(x)); }

// ---------------------------------------------------------------------------
// K1: right-scan. Column-separable: block b owns columns [4b, 4b+4) of R in a
// 64KB LDS slab (fp32) and applies all 128 steps sequentially. Writes
// Rt16 = R^T in bf16 (coalesced rows). Os is fp32.
// ---------------------------------------------------------------------------
__global__ __launch_bounds__(64) void rscan_kernel(const float* __restrict__ Os,
                                                   const int* __restrict__ sel,
                                                   bf16* __restrict__ Rt16) {
    __shared__ float slab[N * 4];  // slab[row*4 + cc] = R[row][c0+cc]
    const int t = threadIdx.x;
    const int cc = t & 3;
    const int a = t >> 2;
    const int c0 = blockIdx.x * 4;

    for (int r = t; r < N * 4; r += 64) slab[r] = 0.0f;
    __syncthreads();
    if (t < 4) slab[(c0 + t) * 4 + t] = 1.0f;
    __syncthreads();

    int selr[16];
    float orow[16];
#pragma unroll
    for (int i = 0; i < 16; i++) selr[i] = sel[i];
#pragma unroll
    for (int i = 0; i < 16; i++) orow[i] = Os[a * 16 + i];

    for (int l = 0; l < LSTEPS; l++) {
        float v = 0.0f;
#pragma unroll
        for (int i = 0; i < 16; i++) v += orow[i] * slab[selr[i] * 4 + cc];
        const int wrow = selr[a];
        int seln[16] = {0};
        float orown[16] = {0.f};
        if (l + 1 < LSTEPS) {
#pragma unroll
            for (int i = 0; i < 16; i++) seln[i] = sel[(l + 1) * 16 + i];
#pragma unroll
            for (int i = 0; i < 16; i++) orown[i] = Os[(l + 1) * 256 + a * 16 + i];
        }
        __syncthreads();
        slab[wrow * 4 + cc] = v;
        __syncthreads();
#pragma unroll
        for (int i = 0; i < 16; i++) { selr[i] = seln[i]; orow[i] = orown[i]; }
    }

    // write out R^T rows (coalesced): Rt16[c][r] = R[r][c]
    for (int ccw = 0; ccw < 4; ccw++) {
        bf16* dst = Rt16 + (size_t)(c0 + ccw) * N;
        for (int r = t; r < N; r += 64) dst[r] = f2bf(slab[r * 4 + ccw]);
    }
}

// ---------------------------------------------------------------------------
// K2: flags/ranks via binary search over the sorted index lists.
// ---------------------------------------------------------------------------
__global__ void prep_kernel(const int* __restrict__ act, const int* __restrict__ inact,
                            int* __restrict__ flags, int* __restrict__ rank) {
    int i = blockIdx.x * blockDim.x + threadIdx.x;
    if (i >= N) return;
    int lo = 0, hi = NACT - 1, f = 0, r = -1;
    while (lo <= hi) {
        int mid = (lo + hi) >> 1, v = act[mid];
        if (v == i) { f = 1; r = mid; break; }
        if (v < i) lo = mid + 1; else hi = mid - 1;
    }
    if (!f) {
        lo = 0; hi = NIN - 1;
        while (lo <= hi) {
            int mid = (lo + hi) >> 1, v = inact[mid];
            if (v == i) { r = mid; break; }
            if (v < i) lo = mid + 1; else hi = mid - 1;
        }
    }
    flags[i] = f;
    rank[i] = r;
}

// ---------------------------------------------------------------------------
// K3: Rt16 (bf16, = R^T) -> R16 (bf16, transposed). 64x64 tiles via LDS.
// ---------------------------------------------------------------------------
__global__ __launch_bounds__(256) void transcast_kernel(const bf16* __restrict__ Rt16,
                                                        bf16* __restrict__ R16) {
    __shared__ ushort tile[64][65];
    const int t = threadIdx.x;
    const int bx = blockIdx.x, by = blockIdx.y;
    const int tr = t >> 4;
    const int tc = (t & 15) * 4;
#pragma unroll
    for (int k = 0; k < 4; k++) {
        int r = tr + 16 * k;
        const ushort* src = (const ushort*)Rt16 + (size_t)(by * 64 + r) * N + bx * 64 + tc;
        ushort4 v = *(const ushort4*)src;
        tile[r][tc + 0] = v.x; tile[r][tc + 1] = v.y;
        tile[r][tc + 2] = v.z; tile[r][tc + 3] = v.w;
    }
    __syncthreads();
#pragma unroll
    for (int k = 0; k < 4; k++) {
        int r = tr + 16 * k;
        ushort4 w;
        w.x = tile[tc + 0][r];
        w.y = tile[tc + 1][r];
        w.z = tile[tc + 2][r];
        w.w = tile[tc + 3][r];
        *(ushort4*)((ushort*)R16 + (size_t)(bx * 64 + r) * N + by * 64 + tc) = w;
    }
}

// ---------------------------------------------------------------------------
// castA: fp32 A -> bf16 A16.
// ---------------------------------------------------------------------------
__global__ __launch_bounds__(256) void castA_kernel(const float* __restrict__ A,
                                                    bf16* __restrict__ A16) {
    const size_t i = ((size_t)blockIdx.x * 256 + threadIdx.x) * 4;
    float4 v = *(const float4*)(A + i);
    ushort4 o;
    o.x = f2us(v.x); o.y = f2us(v.y); o.z = f2us(v.z); o.w = f2us(v.w);
    *(ushort4*)((ushort*)A16 + i) = o;
}

// ---------------------------------------------------------------------------
// K4: scatter rows of R (bf16) to father/mother outputs (fp32).
// ---------------------------------------------------------------------------
__global__ __launch_bounds__(64) void rowgather_kernel(const bf16* __restrict__ R16,
                                                       const int* __restrict__ flags,
                                                       const int* __restrict__ rank,
                                                       float* __restrict__ father,
                                                       float* __restrict__ mother) {
    const int i = blockIdx.x;
    const int t = threadIdx.x;
    float* dst = flags[i] ? (father + (size_t)rank[i] * N) : (mother + (size_t)rank[i] * N);
    const ushort* src = (const ushort*)(R16 + (size_t)i * N);
    for (int j = t * 4; j < N; j += 64 * 4) {
        ushort4 v = *(const ushort4*)(src + j);
        float4 o;
        o.x = us2f(v.x); o.y = us2f(v.y); o.z = us2f(v.z); o.w = us2f(v.w);
        *(float4*)(dst + j) = o;
    }
}

// ---------------------------------------------------------------------------
// K6: wavelets. Block l: u = St[drp[l],:], then apply steps 0..l.
// ---------------------------------------------------------------------------
__global__ __launch_bounds__(64) void wavelet_kernel(const bf16* __restrict__ St,
                                                     const float* __restrict__ Os,
                                                     const int* __restrict__ sel,
                                                     const int* __restrict__ drp,
                                                     float* __restrict__ wout) {
    __shared__ float u[N];
    const int t = threadIdx.x;
    const int l = blockIdx.x;
    const int d = drp[l];
    const ushort* src = (const ushort*)(St + (size_t)d * N);
    for (int j = t; j < N; j += 64) u[j] = us2f(src[j]);
    __syncthreads();
    for (int m = 0; m <= l; m++) {
        float v = 0.0f;
        int wrow = 0;
        if (t < 16) {
#pragma unroll
            for (int i = 0; i < 16; i++) {
                int si = sel[m * 16 + i];
                v += Os[m * 256 + t * 16 + i] * u[si];
            }
            wrow = sel[m * 16 + t];
        }
        __syncthreads();
        if (t < 16) u[wrow] = v;
        __syncthreads();
    }
    float* dst = wout + (size_t)l * N;
    for (int j = t; j < N; j += 64) dst[j] = u[j];
}

// ---------------------------------------------------------------------------
// K8: mask/core. Reads AL16 (bf16). Writes: core rows (fp32, if active),
// masked D (fp32) to out_D, masked D16 (bf16) for the K9 GEMM.
// ---------------------------------------------------------------------------
__global__ __launch_bounds__(256) void maskcore_kernel(const bf16* __restrict__ AL16,
                                                       const int* __restrict__ flags,
                                                       const int* __restrict__ rank,
                                                       float* __restrict__ Dout,
                                                       bf16* __restrict__ D16,
                                                       float* __restrict__ core) {
    const int i = blockIdx.y;
    const int j0 = (blockIdx.x * 256 + threadIdx.x) * 4;
    const int fi = flags[i];
    const int ri = rank[i];
    ushort4 v = *(const ushort4*)((const ushort*)AL16 + (size_t)i * N + j0);
    float4 vf;
    vf.x = us2f(v.x); vf.y = us2f(v.y); vf.z = us2f(v.z); vf.w = us2f(v.w);
    if (fi) *(float4*)(core + (size_t)ri * N + j0) = vf;
    const int4 fj = *(const int4*)(flags + j0);
    bool k0 = (i == j0 + 0) || (fi && fj.x);
    bool k1 = (i == j0 + 1) || (fi && fj.y);
    bool k2 = (i == j0 + 2) || (fi && fj.z);
    bool k3 = (i == j0 + 3) || (fi && fj.w);
    float4 df;
    df.x = k0 ? vf.x : 0.0f; df.y = k1 ? vf.y : 0.0f;
    df.z = k2 ? vf.z : 0.0f; df.w = k3 ? vf.w : 0.0f;
    *(float4*)(Dout + (size_t)i * N + j0) = df;
    ushort4 dv;
    dv.x = k0 ? v.x : (ushort)0; dv.y = k1 ? v.y : (ushort)0;
    dv.z = k2 ? v.z : (ushort)0; dv.w = k3 ? v.w : (ushort)0;
    *(ushort4*)((ushort*)D16 + (size_t)i * N + j0) = dv;
}

// ---------------------------------------------------------------------------
// GEMM v2: C[M,N] = Amat @ Bt^T, bf16 in, fp32 acc, bf16/fp32 out.
// 256x256 tile, BK=32, 512 threads (8 waves, 2Mx4N), per-wave 128x64 output.
// T2: XOR granule swizzle (phys 16B slot = logical ^ (row&3)); applied on the
//     pre-swizzled GLOBAL source (LDS dest of global_load_lds stays linear)
//     and on the ds_read_b128 address. Conflict-free frag reads.
// T3/T4: 4-buffer LDS ring (4 x 32KB = 128KB), 3 tiles in flight, counted
//     s_waitcnt vmcnt(8) once per tile (never 0 in main loop), raw s_barrier.
// T5: s_setprio(1) around each 16-MFMA cluster.
// Safety: iter t reads buf[t&3]; in-flight writes target (t+1..t+3)&3 only;
// vmcnt(8) at end of iter t retires everything through tile t+1.
// ---------------------------------------------------------------------------
#define GBM 256
#define GBK 32
#define GNT (N / GBK)

template <bool F32OUT>
__global__ __launch_bounds__(512) void gemm256_kernel(const bf16* __restrict__ Amat,
                                                      const bf16* __restrict__ Bt,
                                                      void* __restrict__ Cv) {
    __shared__ bf16 lds[4][2][GBM * GBK];  // [buf][A/B][256*32] = 128 KB

    const int t = threadIdx.x;
    const int lane = t & 63;
    const int wave = t >> 6;   // 0..7
    const int wm = wave >> 2;  // 0..1
    const int wn = wave & 3;   // 0..3
    const int rowBase = blockIdx.y * GBM;
    const int colBase = blockIdx.x * GBM;

    // staging lane geometry: instruction idx covers rows [idx*16, idx*16+16);
    // lane l: row = idx*16 + (l>>2), physical slot l&3, logical granule
    // (l&3)^((l>>2)&3). LDS dest linear (wave-uniform base + lane*16).
    const int sr = lane >> 2;
    const int sgo = (((lane & 3) ^ (sr & 3)) << 3);  // element offset of logical granule
    const int w2 = wave * 2;

    // frag-read lane geometry: row = ... + (lane&15), logical granule lane>>4,
    // physical slot = (lane>>4) ^ (row&3) = (lane>>4) ^ (lane&3).
    const int frow = lane & 15;
    const int fslot = (((lane >> 4) ^ (lane & 3)) << 4);
    const int aoff0 = (wm * 128 + frow) * 64 + fslot;
    const int boff0 = (wn * 64 + frow) * 64 + fslot;

    floatx4 acc[8][4] = {};

#define G_STAGE(bufIdx, opIdx, gbase, rowb, kk0)                                                   \
    do {                                                                                           \
        const bf16* g0_ = (gbase) + (size_t)((rowb) + w2 * 16 + sr) * N + (kk0) + sgo;             \
        const bf16* g1_ = g0_ + 16 * N;                                                            \
        char* l0_ = (char*)&lds[bufIdx][opIdx][0] + w2 * 1024;                                     \
        __builtin_amdgcn_global_load_lds((const __attribute__((address_space(1))) void*)g0_,       \
                                         (__attribute__((address_space(3))) void*)l0_, 16, 0, 0);  \
        __builtin_amdgcn_global_load_lds((const __attribute__((address_space(1))) void*)g1_,       \
                                         (__attribute__((address_space(3))) void*)(l0_ + 1024),    \
                                         16, 0, 0);                                                \
    } while (0)

    // prologue: stage tiles 0,1,2 -> buf 0,1,2 (12 load-instructions/wave)
#pragma unroll
    for (int p = 0; p < 3; p++) {
        G_STAGE(p, 0, Amat, rowBase, p * GBK);
        G_STAGE(p, 1, Bt, colBase, p * GBK);
    }
    asm volatile("s_waitcnt vmcnt(8)" ::: "memory");  // tile 0 landed
    __builtin_amdgcn_s_barrier();

    for (int tt = 0; tt < GNT; tt++) {
        const int buf = tt & 3;
        const char* lA = (const char*)&lds[buf][0][0];
        const char* lB = (const char*)&lds[buf][1][0];
        const int nbuf = (tt + 3) & 3;
        const bool pf = (tt + 3) < GNT;
        const int nk0 = (tt + 3) * GBK;

        // ---- phase 1: stage A(t+3); read af[0..3]+bfv; MFMA mi 0..3 ----
        if (pf) G_STAGE(nbuf, 0, Amat, rowBase, nk0);
        short8 af[4], bfv[4];
#pragma unroll
        for (int mi = 0; mi < 4; mi++) af[mi] = *(const short8*)(lA + aoff0 + mi * 1024);
#pragma unroll
        for (int ni = 0; ni < 4; ni++) bfv[ni] = *(const short8*)(lB + boff0 + ni * 1024);
        __builtin_amdgcn_s_barrier();
        asm volatile("s_waitcnt lgkmcnt(0)" ::: "memory");
        __builtin_amdgcn_s_setprio(1);
#pragma unroll
        for (int mi = 0; mi < 4; mi++)
#pragma unroll
            for (int ni = 0; ni < 4; ni++)
                acc[mi][ni] =
                    __builtin_amdgcn_mfma_f32_16x16x32_bf16(af[mi], bfv[ni], acc[mi][ni], 0, 0, 0);
        __builtin_amdgcn_s_setprio(0);
        __builtin_amdgcn_s_barrier();

        // ---- phase 2: stage B(t+3); read af[4..7]; MFMA mi 4..7 ----
        if (pf) G_STAGE(nbuf, 1, Bt, colBase, nk0);
        short8 ag[4];
#pragma unroll
        for (int mi = 0; mi < 4; mi++) ag[mi] = *(const short8*)(lA + aoff0 + (mi + 4) * 1024);
        __builtin_amdgcn_s_barrier();
        asm volatile("s_waitcnt lgkmcnt(0)" ::: "memory");
        __builtin_amdgcn_s_setprio(1);
#pragma unroll
        for (int mi = 0; mi < 4; mi++)
#pragma unroll
            for (int ni = 0; ni < 4; ni++)
                acc[mi + 4][ni] = __builtin_amdgcn_mfma_f32_16x16x32_bf16(ag[mi], bfv[ni],
                                                                          acc[mi + 4][ni], 0, 0, 0);
        __builtin_amdgcn_s_setprio(0);
        // counted vmcnt: keep tiles t+2, t+3 (8 instr) in flight; t+1 landed.
        asm volatile("s_waitcnt vmcnt(8)" ::: "memory");
        __builtin_amdgcn_s_barrier();
    }
#undef G_STAGE

    const int crow = (lane >> 4) * 4;
    const int ccol = lane & 15;
    const int rb = rowBase + wm * 128;
    const int cb = colBase + wn * 64;
#pragma unroll
    for (int mi = 0; mi < 8; mi++)
#pragma unroll
        for (int ni = 0; ni < 4; ni++)
#pragma unroll
            for (int r = 0; r < 4; r++) {
                const int gr = rb + mi * 16 + crow + r;
                const int gc = cb + ni * 16 + ccol;
                if (F32OUT)
                    ((float*)Cv)[(size_t)gr * N + gc] = acc[mi][ni][r];
                else
                    ((bf16*)Cv)[(size_t)gr * N + gc] = f2bf(acc[mi][ni][r]);
            }
}

// ---------------------------------------------------------------------------
// Dtypes per the reference: A, Os fp32; sel/drp/act/inact int32; outputs fp32.
// Internal compute bf16 MFMA with fp32 accumulate (error << 2% threshold).
//
// Workspace (96 MB): [0,32)MB A16 -> AL16 -> Tt16 (time-shared);
//                    [32,64)MB R16; [64,96)MB Rt16.
// Output-region scratch: St16 in A_rec[0,32MB); D16 in A_rec[32,64MB) bytes
// (both dead before K10 overwrites); flags/rank in wavelets region (dead
// before K6 overwrites).
// ---------------------------------------------------------------------------
extern "C" void kernel_launch(void* const* d_in, const int* in_sizes, int n_in,
                              void* d_out, int out_size, void* d_ws, size_t ws_size,
                              hipStream_t stream) {
    const float* A = (const float*)d_in[0];
    const float* Os = (const float*)d_in[1];
    const int* sel = (const int*)d_in[2];
    const int* drp = (const int*)d_in[3];
    const int* act = (const int*)d_in[4];
    const int* inact = (const int*)d_in[5];

    float* out = (float*)d_out;
    float* out_Arec = out;                          // 4096*4096
    float* out_D    = out + 16777216;               // 4096*4096
    float* out_wav  = out + 33554432;               // 128*4096
    float* out_core = out + 34078720;               // 3968*4096
    float* out_moth = out + 50331648;               // 128*4096
    float* out_fath = out + 50855936;               // 3968*4096

    char* ws = (char*)d_ws;
    const size_t MB = 1024 * 1024;
    bf16* A16  = (bf16*)(ws + 0);             // dead after K5
    bf16* AL16 = (bf16*)(ws + 0);             // written K7, dead after K8
    bf16* Tt16 = (bf16*)(ws + 0);             // written K9, dead after K10
    bf16* R16  = (bf16*)(ws + 32 * MB);
    bf16* Rt16 = (bf16*)(ws + 64 * MB);
    bf16* St16 = (bf16*)out_Arec;                   // A_rec bytes [0,32MB)
    bf16* D16  = (bf16*)(out_Arec + 8388608);       // A_rec bytes [32,64MB)
    int* flags = (int*)out_wav;                     // dead before K6
    int* rank  = flags + N;

    // K1: sequential right-scan -> Rt16 (= R^T, bf16)
    rscan_kernel<<<dim3(N / 4), dim3(64), 0, stream>>>(Os, sel, Rt16);
    // K2: active flags + ranks (scratch in wavelets region)
    prep_kernel<<<dim3(16), dim3(256), 0, stream>>>(act, inact, flags, rank);
    // K3: R16 = transpose(Rt16)
    transcast_kernel<<<dim3(64, 64), dim3(256), 0, stream>>>(Rt16, R16);
    // K4: father/mother rows of R (fp32 out)
    rowgather_kernel<<<dim3(N), dim3(64), 0, stream>>>(R16, flags, rank, out_fath, out_moth);
    // castA: A fp32 -> bf16
    castA_kernel<<<dim3(16384), dim3(256), 0, stream>>>(A, A16);
    // K5: St = R @ A (A symmetric) -> A_rec region scratch
    gemm256_kernel<false><<<dim3(16, 16), dim3(512), 0, stream>>>(R16, A16, St16);
    // K7: A_L = R @ St^T -> ws slot 0 (A16 dead)
    gemm256_kernel<false><<<dim3(16, 16), dim3(512), 0, stream>>>(R16, St16, AL16);
    // K8: core rows (fp32) + masked D (fp32) + masked D16 (bf16)
    maskcore_kernel<<<dim3(4, N), dim3(256), 0, stream>>>(AL16, flags, rank, out_D, D16, out_core);
    // K6: wavelets from St rows (fp32 out; overwrites flags/rank — dead)
    wavelet_kernel<<<dim3(LSTEPS), dim3(64), 0, stream>>>(St16, Os, sel, drp, out_wav);
    // K9: Tt = R^T @ D (D symmetric to bf16 noise) -> ws slot 0 (AL16 dead)
    gemm256_kernel<false><<<dim3(16, 16), dim3(512), 0, stream>>>(Rt16, D16, Tt16);
    // K10: A_rec = Tt @ Rt^T = R^T D R -> fp32 out (St16/D16 scratch dead)
    gemm256_kernel<true><<<dim3(16, 16), dim3(512), 0, stream>>>(Tt16, Rt16, out_Arec);
}

// Round 2
// 998.479 us; speedup vs baseline: 1.2936x; 1.0476x over previous
//
#include <hip/hip_runtime.h>
#include <hip/hip_bf16.h>
#include <stdint.h>

#define N 4096
#define LSTEPS 128
#define KSEL 16
#define NACT 3968
#define NIN 128

typedef __hip_bfloat16 bf16;
typedef __attribute__((ext_vector_type(8))) short short8;
typedef __attribute__((ext_vector_type(4))) float floatx4;

static __device__ __forceinline__ bf16 f2bf(float x) { return __float2bfloat16(x); }
static __device__ __forceinline__ float us2f(ushort u) { return __uint_as_float(((unsigned)u) << 16); }
static __device__ __forceinline__ ushort f2us(float x) { return __bfloat16_as_ushort(__float2bfloat16(x)); }

// ---------------------------------------------------------------------------
// K1: right-scan. Column-separable: block b owns columns [4b, 4b+4) of R in a
// 64KB LDS slab (fp32) and applies all 128 steps sequentially. Writes
// Rt16 = R^T in bf16 (coalesced rows). Os is fp32.
// ---------------------------------------------------------------------------
__global__ __launch_bounds__(64) void rscan_kernel(const float* __restrict__ Os,
                                                   const int* __restrict__ sel,
                                                   bf16* __restrict__ Rt16) {
    __shared__ float slab[N * 4];  // slab[row*4 + cc] = R[row][c0+cc]
    const int t = threadIdx.x;
    const int cc = t & 3;
    const int a = t >> 2;
    const int c0 = blockIdx.x * 4;

    for (int r = t; r < N * 4; r += 64) slab[r] = 0.0f;
    __syncthreads();
    if (t < 4) slab[(c0 + t) * 4 + t] = 1.0f;
    __syncthreads();

    int selr[16];
    float orow[16];
#pragma unroll
    for (int i = 0; i < 16; i++) selr[i] = sel[i];
#pragma unroll
    for (int i = 0; i < 16; i++) orow[i] = Os[a * 16 + i];

    for (int l = 0; l < LSTEPS; l++) {
        float v = 0.0f;
#pragma unroll
        for (int i = 0; i < 16; i++) v += orow[i] * slab[selr[i] * 4 + cc];
        const int wrow = selr[a];
        int seln[16] = {0};
        float orown[16] = {0.f};
        if (l + 1 < LSTEPS) {
#pragma unroll
            for (int i = 0; i < 16; i++) seln[i] = sel[(l + 1) * 16 + i];
#pragma unroll
            for (int i = 0; i < 16; i++) orown[i] = Os[(l + 1) * 256 + a * 16 + i];
        }
        __syncthreads();
        slab[wrow * 4 + cc] = v;
        __syncthreads();
#pragma unroll
        for (int i = 0; i < 16; i++) { selr[i] = seln[i]; orow[i] = orown[i]; }
    }

    // write out R^T rows (coalesced): Rt16[c][r] = R[r][c]
    for (int ccw = 0; ccw < 4; ccw++) {
        bf16* dst = Rt16 + (size_t)(c0 + ccw) * N;
        for (int r = t; r < N; r += 64) dst[r] = f2bf(slab[r * 4 + ccw]);
    }
}

// ---------------------------------------------------------------------------
// K2: flags/ranks via binary search over the sorted index lists.
// ---------------------------------------------------------------------------
__global__ void prep_kernel(const int* __restrict__ act, const int* __restrict__ inact,
                            int* __restrict__ flags, int* __restrict__ rank) {
    int i = blockIdx.x * blockDim.x + threadIdx.x;
    if (i >= N) return;
    int lo = 0, hi = NACT - 1, f = 0, r = -1;
    while (lo <= hi) {
        int mid = (lo + hi) >> 1, v = act[mid];
        if (v == i) { f = 1; r = mid; break; }
        if (v < i) lo = mid + 1; else hi = mid - 1;
    }
    if (!f) {
        lo = 0; hi = NIN - 1;
        while (lo <= hi) {
            int mid = (lo + hi) >> 1, v = inact[mid];
            if (v == i) { r = mid; break; }
            if (v < i) lo = mid + 1; else hi = mid - 1;
        }
    }
    flags[i] = f;
    rank[i] = r;
}

// ---------------------------------------------------------------------------
// K3: Rt16 (bf16, = R^T) -> R16 (bf16, transposed). 64x64 tiles via LDS.
// ---------------------------------------------------------------------------
__global__ __launch_bounds__(256) void transcast_kernel(const bf16* __restrict__ Rt16,
                                                        bf16* __restrict__ R16) {
    __shared__ ushort tile[64][65];
    const int t = threadIdx.x;
    const int bx = blockIdx.x, by = blockIdx.y;
    const int tr = t >> 4;
    const int tc = (t & 15) * 4;
#pragma unroll
    for (int k = 0; k < 4; k++) {
        int r = tr + 16 * k;
        const ushort* src = (const ushort*)Rt16 + (size_t)(by * 64 + r) * N + bx * 64 + tc;
        ushort4 v = *(const ushort4*)src;
        tile[r][tc + 0] = v.x; tile[r][tc + 1] = v.y;
        tile[r][tc + 2] = v.z; tile[r][tc + 3] = v.w;
    }
    __syncthreads();
#pragma unroll
    for (int k = 0; k < 4; k++) {
        int r = tr + 16 * k;
        ushort4 w;
        w.x = tile[tc + 0][r];
        w.y = tile[tc + 1][r];
        w.z = tile[tc + 2][r];
        w.w = tile[tc + 3][r];
        *(ushort4*)((ushort*)R16 + (size_t)(bx * 64 + r) * N + by * 64 + tc) = w;
    }
}

// ---------------------------------------------------------------------------
// castA: fp32 A -> bf16 A16.
// ---------------------------------------------------------------------------
__global__ __launch_bounds__(256) void castA_kernel(const float* __restrict__ A,
                                                    bf16* __restrict__ A16) {
    const size_t i = ((size_t)blockIdx.x * 256 + threadIdx.x) * 4;
    float4 v = *(const float4*)(A + i);
    ushort4 o;
    o.x = f2us(v.x); o.y = f2us(v.y); o.z = f2us(v.z); o.w = f2us(v.w);
    *(ushort4*)((ushort*)A16 + i) = o;
}

// ---------------------------------------------------------------------------
// K4: scatter rows of R (bf16) to father/mother outputs (fp32).
// ---------------------------------------------------------------------------
__global__ __launch_bounds__(64) void rowgather_kernel(const bf16* __restrict__ R16,
                                                       const int* __restrict__ flags,
                                                       const int* __restrict__ rank,
                                                       float* __restrict__ father,
                                                       float* __restrict__ mother) {
    const int i = blockIdx.x;
    const int t = threadIdx.x;
    float* dst = flags[i] ? (father + (size_t)rank[i] * N) : (mother + (size_t)rank[i] * N);
    const ushort* src = (const ushort*)(R16 + (size_t)i * N);
    for (int j = t * 4; j < N; j += 64 * 4) {
        ushort4 v = *(const ushort4*)(src + j);
        float4 o;
        o.x = us2f(v.x); o.y = us2f(v.y); o.z = us2f(v.z); o.w = us2f(v.w);
        *(float4*)(dst + j) = o;
    }
}

// ---------------------------------------------------------------------------
// K6: wavelets. Block l: u = St[drp[l],:], then apply steps 0..l.
// ---------------------------------------------------------------------------
__global__ __launch_bounds__(64) void wavelet_kernel(const bf16* __restrict__ St,
                                                     const float* __restrict__ Os,
                                                     const int* __restrict__ sel,
                                                     const int* __restrict__ drp,
                                                     float* __restrict__ wout) {
    __shared__ float u[N];
    const int t = threadIdx.x;
    const int l = blockIdx.x;
    const int d = drp[l];
    const ushort* src = (const ushort*)(St + (size_t)d * N);
    for (int j = t; j < N; j += 64) u[j] = us2f(src[j]);
    __syncthreads();
    for (int m = 0; m <= l; m++) {
        float v = 0.0f;
        int wrow = 0;
        if (t < 16) {
#pragma unroll
            for (int i = 0; i < 16; i++) {
                int si = sel[m * 16 + i];
                v += Os[m * 256 + t * 16 + i] * u[si];
            }
            wrow = sel[m * 16 + t];
        }
        __syncthreads();
        if (t < 16) u[wrow] = v;
        __syncthreads();
    }
    float* dst = wout + (size_t)l * N;
    for (int j = t; j < N; j += 64) dst[j] = u[j];
}

// ---------------------------------------------------------------------------
// K8: mask/core. Reads AL16 (bf16). Writes: core rows (fp32, if active),
// masked D (fp32) to out_D, masked D16 (bf16) for the K9 GEMM.
// ---------------------------------------------------------------------------
__global__ __launch_bounds__(256) void maskcore_kernel(const bf16* __restrict__ AL16,
                                                       const int* __restrict__ flags,
                                                       const int* __restrict__ rank,
                                                       float* __restrict__ Dout,
                                                       bf16* __restrict__ D16,
                                                       float* __restrict__ core) {
    const int i = blockIdx.y;
    const int j0 = (blockIdx.x * 256 + threadIdx.x) * 4;
    const int fi = flags[i];
    const int ri = rank[i];
    ushort4 v = *(const ushort4*)((const ushort*)AL16 + (size_t)i * N + j0);
    float4 vf;
    vf.x = us2f(v.x); vf.y = us2f(v.y); vf.z = us2f(v.z); vf.w = us2f(v.w);
    if (fi) *(float4*)(core + (size_t)ri * N + j0) = vf;
    const int4 fj = *(const int4*)(flags + j0);
    bool k0 = (i == j0 + 0) || (fi && fj.x);
    bool k1 = (i == j0 + 1) || (fi && fj.y);
    bool k2 = (i == j0 + 2) || (fi && fj.z);
    bool k3 = (i == j0 + 3) || (fi && fj.w);
    float4 df;
    df.x = k0 ? vf.x : 0.0f; df.y = k1 ? vf.y : 0.0f;
    df.z = k2 ? vf.z : 0.0f; df.w = k3 ? vf.w : 0.0f;
    *(float4*)(Dout + (size_t)i * N + j0) = df;
    ushort4 dv;
    dv.x = k0 ? v.x : (ushort)0; dv.y = k1 ? v.y : (ushort)0;
    dv.z = k2 ? v.z : (ushort)0; dv.w = k3 ? v.w : (ushort)0;
    *(ushort4*)((ushort*)D16 + (size_t)i * N + j0) = dv;
}

// ---------------------------------------------------------------------------
// GEMM v2.1: C[M,N] = Amat @ Bt^T, bf16 in, fp32 acc, bf16/fp32 out.
// 256x256 tile, BK=32, 512 threads (8 waves, 2Mx4N), per-wave 128x64 output.
// T2 (upgraded): XOR granule swizzle phys_slot = logical ^ ((row>>1)&3).
//     Bank math: 64B rows split banks by row parity (even rows banks 0-15,
//     odd rows 16-31). Bank-quad of a 16B granule = (row&1)*4 + slot. With
//     slot = g ^ ((row>>1)&3), any 8 consecutive rows enumerate all 8 quads,
//     so a 16-lane b128 read group is 2 lanes/quad = 2-way = free (m136).
//     (Previous ^(row&3) swizzle collapsed to 4 quads x4 = 4-way, 1.58x.)
//     Applied on the pre-swizzled GLOBAL source (LDS dest of global_load_lds
//     stays linear) and on the ds_read_b128 address.
// T3/T4: 4-buffer LDS ring (4 x 32KB = 128KB), 3 tiles in flight, counted
//     s_waitcnt vmcnt(8) once per tile (never 0 in main loop), raw s_barrier.
// T5: s_setprio(1) around each 16-MFMA cluster.
// Safety: iter t reads buf[t&3]; in-flight writes target (t+1..t+3)&3 only;
// vmcnt(8) at end of iter t retires everything through tile t+1.
// ---------------------------------------------------------------------------
#define GBM 256
#define GBK 32
#define GNT (N / GBK)

template <bool F32OUT>
__global__ __launch_bounds__(512) void gemm256_kernel(const bf16* __restrict__ Amat,
                                                      const bf16* __restrict__ Bt,
                                                      void* __restrict__ Cv) {
    __shared__ bf16 lds[4][2][GBM * GBK];  // [buf][A/B][256*32] = 128 KB

    const int t = threadIdx.x;
    const int lane = t & 63;
    const int wave = t >> 6;   // 0..7
    const int wm = wave >> 2;  // 0..1
    const int wn = wave & 3;   // 0..3
    const int rowBase = blockIdx.y * GBM;
    const int colBase = blockIdx.x * GBM;

    // staging lane geometry: instruction idx covers rows [idx*16, idx*16+16);
    // lane l: row = idx*16 + (l>>2), physical slot l&3, logical granule
    // (l&3) ^ ((row>>1)&3) = (l&3) ^ ((l>>3)&3). LDS dest linear
    // (wave-uniform base + lane*16).
    const int sr = lane >> 2;
    const int sgo = (((lane & 3) ^ ((lane >> 3) & 3)) << 3);  // element offset of logical granule
    const int w2 = wave * 2;

    // frag-read lane geometry: row = ... + (lane&15), logical granule lane>>4,
    // physical slot = (lane>>4) ^ ((row>>1)&3) = (lane>>4) ^ ((lane>>1)&3).
    const int frow = lane & 15;
    const int fslot = (((lane >> 4) ^ ((lane >> 1) & 3)) << 4);
    const int aoff0 = (wm * 128 + frow) * 64 + fslot;
    const int boff0 = (wn * 64 + frow) * 64 + fslot;

    floatx4 acc[8][4] = {};

#define G_STAGE(bufIdx, opIdx, gbase, rowb, kk0)                                                   \
    do {                                                                                           \
        const bf16* g0_ = (gbase) + (size_t)((rowb) + w2 * 16 + sr) * N + (kk0) + sgo;             \
        const bf16* g1_ = g0_ + 16 * N;                                                            \
        char* l0_ = (char*)&lds[bufIdx][opIdx][0] + w2 * 1024;                                     \
        __builtin_amdgcn_global_load_lds((const __attribute__((address_space(1))) void*)g0_,       \
                                         (__attribute__((address_space(3))) void*)l0_, 16, 0, 0);  \
        __builtin_amdgcn_global_load_lds((const __attribute__((address_space(1))) void*)g1_,       \
                                         (__attribute__((address_space(3))) void*)(l0_ + 1024),    \
                                         16, 0, 0);                                                \
    } while (0)

    // prologue: stage tiles 0,1,2 -> buf 0,1,2 (12 load-instructions/wave)
#pragma unroll
    for (int p = 0; p < 3; p++) {
        G_STAGE(p, 0, Amat, rowBase, p * GBK);
        G_STAGE(p, 1, Bt, colBase, p * GBK);
    }
    asm volatile("s_waitcnt vmcnt(8)" ::: "memory");  // tile 0 landed
    __builtin_amdgcn_s_barrier();

    for (int tt = 0; tt < GNT; tt++) {
        const int buf = tt & 3;
        const char* lA = (const char*)&lds[buf][0][0];
        const char* lB = (const char*)&lds[buf][1][0];
        const int nbuf = (tt + 3) & 3;
        const bool pf = (tt + 3) < GNT;
        const int nk0 = (tt + 3) * GBK;

        // ---- phase 1: stage A(t+3); read af[0..3]+bfv; MFMA mi 0..3 ----
        if (pf) G_STAGE(nbuf, 0, Amat, rowBase, nk0);
        short8 af[4], bfv[4];
#pragma unroll
        for (int mi = 0; mi < 4; mi++) af[mi] = *(const short8*)(lA + aoff0 + mi * 1024);
#pragma unroll
        for (int ni = 0; ni < 4; ni++) bfv[ni] = *(const short8*)(lB + boff0 + ni * 1024);
        __builtin_amdgcn_s_barrier();
        asm volatile("s_waitcnt lgkmcnt(0)" ::: "memory");
        __builtin_amdgcn_s_setprio(1);
#pragma unroll
        for (int mi = 0; mi < 4; mi++)
#pragma unroll
            for (int ni = 0; ni < 4; ni++)
                acc[mi][ni] =
                    __builtin_amdgcn_mfma_f32_16x16x32_bf16(af[mi], bfv[ni], acc[mi][ni], 0, 0, 0);
        __builtin_amdgcn_s_setprio(0);
        __builtin_amdgcn_s_barrier();

        // ---- phase 2: stage B(t+3); read af[4..7]; MFMA mi 4..7 ----
        if (pf) G_STAGE(nbuf, 1, Bt, colBase, nk0);
        short8 ag[4];
#pragma unroll
        for (int mi = 0; mi < 4; mi++) ag[mi] = *(const short8*)(lA + aoff0 + (mi + 4) * 1024);
        __builtin_amdgcn_s_barrier();
        asm volatile("s_waitcnt lgkmcnt(0)" ::: "memory");
        __builtin_amdgcn_s_setprio(1);
#pragma unroll
        for (int mi = 0; mi < 4; mi++)
#pragma unroll
            for (int ni = 0; ni < 4; ni++)
                acc[mi + 4][ni] = __builtin_amdgcn_mfma_f32_16x16x32_bf16(ag[mi], bfv[ni],
                                                                          acc[mi + 4][ni], 0, 0, 0);
        __builtin_amdgcn_s_setprio(0);
        // counted vmcnt: keep tiles t+2, t+3 (8 instr) in flight; t+1 landed.
        asm volatile("s_waitcnt vmcnt(8)" ::: "memory");
        __builtin_amdgcn_s_barrier();
    }
#undef G_STAGE

    const int crow = (lane >> 4) * 4;
    const int ccol = lane & 15;
    const int rb = rowBase + wm * 128;
    const int cb = colBase + wn * 64;
#pragma unroll
    for (int mi = 0; mi < 8; mi++)
#pragma unroll
        for (int ni = 0; ni < 4; ni++)
#pragma unroll
            for (int r = 0; r < 4; r++) {
                const int gr = rb + mi * 16 + crow + r;
                const int gc = cb + ni * 16 + ccol;
                if (F32OUT)
                    ((float*)Cv)[(size_t)gr * N + gc] = acc[mi][ni][r];
                else
                    ((bf16*)Cv)[(size_t)gr * N + gc] = f2bf(acc[mi][ni][r]);
            }
}

// ---------------------------------------------------------------------------
// Dtypes per the reference: A, Os fp32; sel/drp/act/inact int32; outputs fp32.
// Internal compute bf16 MFMA with fp32 accumulate (error << 2% threshold).
//
// Workspace (96 MB): [0,32)MB A16 -> AL16 -> Tt16 (time-shared);
//                    [32,64)MB R16; [64,96)MB Rt16.
// Output-region scratch: St16 in A_rec[0,32MB); D16 in A_rec[32,64MB) bytes
// (both dead before K10 overwrites); flags/rank in wavelets region (dead
// before K6 overwrites).
// ---------------------------------------------------------------------------
extern "C" void kernel_launch(void* const* d_in, const int* in_sizes, int n_in,
                              void* d_out, int out_size, void* d_ws, size_t ws_size,
                              hipStream_t stream) {
    const float* A = (const float*)d_in[0];
    const float* Os = (const float*)d_in[1];
    const int* sel = (const int*)d_in[2];
    const int* drp = (const int*)d_in[3];
    const int* act = (const int*)d_in[4];
    const int* inact = (const int*)d_in[5];

    float* out = (float*)d_out;
    float* out_Arec = out;                          // 4096*4096
    float* out_D    = out + 16777216;               // 4096*4096
    float* out_wav  = out + 33554432;               // 128*4096
    float* out_core = out + 34078720;               // 3968*4096
    float* out_moth = out + 50331648;               // 128*4096
    float* out_fath = out + 50855936;               // 3968*4096

    char* ws = (char*)d_ws;
    const size_t MB = 1024 * 1024;
    bf16* A16  = (bf16*)(ws + 0);             // dead after K5
    bf16* AL16 = (bf16*)(ws + 0);             // written K7, dead after K8
    bf16* Tt16 = (bf16*)(ws + 0);             // written K9, dead after K10
    bf16* R16  = (bf16*)(ws + 32 * MB);
    bf16* Rt16 = (bf16*)(ws + 64 * MB);
    bf16* St16 = (bf16*)out_Arec;                   // A_rec bytes [0,32MB)
    bf16* D16  = (bf16*)(out_Arec + 8388608);       // A_rec bytes [32,64MB)
    int* flags = (int*)out_wav;                     // dead before K6
    int* rank  = flags + N;

    // K1: sequential right-scan -> Rt16 (= R^T, bf16)
    rscan_kernel<<<dim3(N / 4), dim3(64), 0, stream>>>(Os, sel, Rt16);
    // K2: active flags + ranks (scratch in wavelets region)
    prep_kernel<<<dim3(16), dim3(256), 0, stream>>>(act, inact, flags, rank);
    // K3: R16 = transpose(Rt16)
    transcast_kernel<<<dim3(64, 64), dim3(256), 0, stream>>>(Rt16, R16);
    // K4: father/mother rows of R (fp32 out)
    rowgather_kernel<<<dim3(N), dim3(64), 0, stream>>>(R16, flags, rank, out_fath, out_moth);
    // castA: A fp32 -> bf16
    castA_kernel<<<dim3(16384), dim3(256), 0, stream>>>(A, A16);
    // K5: St = R @ A (A symmetric) -> A_rec region scratch
    gemm256_kernel<false><<<dim3(16, 16), dim3(512), 0, stream>>>(R16, A16, St16);
    // K7: A_L = R @ St^T -> ws slot 0 (A16 dead)
    gemm256_kernel<false><<<dim3(16, 16), dim3(512), 0, stream>>>(R16, St16, AL16);
    // K8: core rows (fp32) + masked D (fp32) + masked D16 (bf16)
    maskcore_kernel<<<dim3(4, N), dim3(256), 0, stream>>>(AL16, flags, rank, out_D, D16, out_core);
    // K6: wavelets from St rows (fp32 out; overwrites flags/rank — dead)
    wavelet_kernel<<<dim3(LSTEPS), dim3(64), 0, stream>>>(St16, Os, sel, drp, out_wav);
    // K9: Tt = R^T @ D (D symmetric to bf16 noise) -> ws slot 0 (AL16 dead)
    gemm256_kernel<false><<<dim3(16, 16), dim3(512), 0, stream>>>(Rt16, D16, Tt16);
    // K10: A_rec = Tt @ Rt^T = R^T D R -> fp32 out (St16/D16 scratch dead)
    gemm256_kernel<true><<<dim3(16, 16), dim3(512), 0, stream>>>(Tt16, Rt16, out_Arec);
}

// Round 3
// 990.207 us; speedup vs baseline: 1.3045x; 1.0084x over previous
//
#include <hip/hip_runtime.h>
#include <hip/hip_bf16.h>
#include <stdint.h>

#define N 4096
#define LSTEPS 128
#define KSEL 16
#define NACT 3968
#define NIN 128

typedef __hip_bfloat16 bf16;
typedef __attribute__((ext_vector_type(8))) short short8;
typedef __attribute__((ext_vector_type(4))) float floatx4;

static __device__ __forceinline__ bf16 f2bf(float x) { return __float2bfloat16(x); }
static __device__ __forceinline__ float us2f(ushort u) { return __uint_as_float(((unsigned)u) << 16); }
static __device__ __forceinline__ ushort f2us(float x) { return __bfloat16_as_ushort(__float2bfloat16(x)); }

// ---------------------------------------------------------------------------
// K1: right-scan. Column-separable: block b owns columns [4b, 4b+4) of R in a
// 64KB LDS slab (fp32) and applies all 128 steps sequentially. Writes
// Rt16 = R^T in bf16 (coalesced rows). Os is fp32.
// v2: batch the 16 LDS reads into an array (independent -> one lgkmcnt wait)
// then explicit 4-deep product tree, instead of a 16-deep serial FMA chain
// with potentially exposed ~120cy LDS latency per link.
// ---------------------------------------------------------------------------
__global__ __launch_bounds__(64) void rscan_kernel(const float* __restrict__ Os,
                                                   const int* __restrict__ sel,
                                                   bf16* __restrict__ Rt16) {
    __shared__ float slab[N * 4];  // slab[row*4 + cc] = R[row][c0+cc]
    const int t = threadIdx.x;
    const int cc = t & 3;
    const int a = t >> 2;
    const int c0 = blockIdx.x * 4;

    for (int r = t; r < N * 4; r += 64) slab[r] = 0.0f;
    __syncthreads();
    if (t < 4) slab[(c0 + t) * 4 + t] = 1.0f;
    __syncthreads();

    int selr[16];
    float orow[16];
#pragma unroll
    for (int i = 0; i < 16; i++) selr[i] = sel[i];
#pragma unroll
    for (int i = 0; i < 16; i++) orow[i] = Os[a * 16 + i];

    for (int l = 0; l < LSTEPS; l++) {
        float p[16];
#pragma unroll
        for (int i = 0; i < 16; i++) p[i] = slab[selr[i] * 4 + cc];
#pragma unroll
        for (int i = 0; i < 16; i++) p[i] *= orow[i];
        const float s0 = (p[0] + p[1]) + (p[2] + p[3]);
        const float s1 = (p[4] + p[5]) + (p[6] + p[7]);
        const float s2 = (p[8] + p[9]) + (p[10] + p[11]);
        const float s3 = (p[12] + p[13]) + (p[14] + p[15]);
        const float v = (s0 + s1) + (s2 + s3);
        const int wrow = selr[a];
        int seln[16] = {0};
        float orown[16] = {0.f};
        if (l + 1 < LSTEPS) {
#pragma unroll
            for (int i = 0; i < 16; i++) seln[i] = sel[(l + 1) * 16 + i];
#pragma unroll
            for (int i = 0; i < 16; i++) orown[i] = Os[(l + 1) * 256 + a * 16 + i];
        }
        __syncthreads();
        slab[wrow * 4 + cc] = v;
        __syncthreads();
#pragma unroll
        for (int i = 0; i < 16; i++) { selr[i] = seln[i]; orow[i] = orown[i]; }
    }

    // write out R^T rows (coalesced): Rt16[c][r] = R[r][c]
    for (int ccw = 0; ccw < 4; ccw++) {
        bf16* dst = Rt16 + (size_t)(c0 + ccw) * N;
        for (int r = t; r < N; r += 64) dst[r] = f2bf(slab[r * 4 + ccw]);
    }
}

// ---------------------------------------------------------------------------
// K2: flags/ranks via binary search over the sorted index lists.
// ---------------------------------------------------------------------------
__global__ void prep_kernel(const int* __restrict__ act, const int* __restrict__ inact,
                            int* __restrict__ flags, int* __restrict__ rank) {
    int i = blockIdx.x * blockDim.x + threadIdx.x;
    if (i >= N) return;
    int lo = 0, hi = NACT - 1, f = 0, r = -1;
    while (lo <= hi) {
        int mid = (lo + hi) >> 1, v = act[mid];
        if (v == i) { f = 1; r = mid; break; }
        if (v < i) lo = mid + 1; else hi = mid - 1;
    }
    if (!f) {
        lo = 0; hi = NIN - 1;
        while (lo <= hi) {
            int mid = (lo + hi) >> 1, v = inact[mid];
            if (v == i) { r = mid; break; }
            if (v < i) lo = mid + 1; else hi = mid - 1;
        }
    }
    flags[i] = f;
    rank[i] = r;
}

// ---------------------------------------------------------------------------
// K3: Rt16 (bf16, = R^T) -> R16 (bf16, transposed). 64x64 tiles via LDS.
// ---------------------------------------------------------------------------
__global__ __launch_bounds__(256) void transcast_kernel(const bf16* __restrict__ Rt16,
                                                        bf16* __restrict__ R16) {
    __shared__ ushort tile[64][65];
    const int t = threadIdx.x;
    const int bx = blockIdx.x, by = blockIdx.y;
    const int tr = t >> 4;
    const int tc = (t & 15) * 4;
#pragma unroll
    for (int k = 0; k < 4; k++) {
        int r = tr + 16 * k;
        const ushort* src = (const ushort*)Rt16 + (size_t)(by * 64 + r) * N + bx * 64 + tc;
        ushort4 v = *(const ushort4*)src;
        tile[r][tc + 0] = v.x; tile[r][tc + 1] = v.y;
        tile[r][tc + 2] = v.z; tile[r][tc + 3] = v.w;
    }
    __syncthreads();
#pragma unroll
    for (int k = 0; k < 4; k++) {
        int r = tr + 16 * k;
        ushort4 w;
        w.x = tile[tc + 0][r];
        w.y = tile[tc + 1][r];
        w.z = tile[tc + 2][r];
        w.w = tile[tc + 3][r];
        *(ushort4*)((ushort*)R16 + (size_t)(bx * 64 + r) * N + by * 64 + tc) = w;
    }
}

// ---------------------------------------------------------------------------
// castA: fp32 A -> bf16 A16.
// ---------------------------------------------------------------------------
__global__ __launch_bounds__(256) void castA_kernel(const float* __restrict__ A,
                                                    bf16* __restrict__ A16) {
    const size_t i = ((size_t)blockIdx.x * 256 + threadIdx.x) * 4;
    float4 v = *(const float4*)(A + i);
    ushort4 o;
    o.x = f2us(v.x); o.y = f2us(v.y); o.z = f2us(v.z); o.w = f2us(v.w);
    *(ushort4*)((ushort*)A16 + i) = o;
}

// ---------------------------------------------------------------------------
// K4: scatter rows of R (bf16) to father/mother outputs (fp32).
// ---------------------------------------------------------------------------
__global__ __launch_bounds__(64) void rowgather_kernel(const bf16* __restrict__ R16,
                                                       const int* __restrict__ flags,
                                                       const int* __restrict__ rank,
                                                       float* __restrict__ father,
                                                       float* __restrict__ mother) {
    const int i = blockIdx.x;
    const int t = threadIdx.x;
    float* dst = flags[i] ? (father + (size_t)rank[i] * N) : (mother + (size_t)rank[i] * N);
    const ushort* src = (const ushort*)(R16 + (size_t)i * N);
    for (int j = t * 4; j < N; j += 64 * 4) {
        ushort4 v = *(const ushort4*)(src + j);
        float4 o;
        o.x = us2f(v.x); o.y = us2f(v.y); o.z = us2f(v.z); o.w = us2f(v.w);
        *(float4*)(dst + j) = o;
    }
}

// ---------------------------------------------------------------------------
// K6: wavelets. Block l: u = St[drp[l],:], then apply steps 0..l.
// v2: batched LDS loads + product tree (same fix as rscan).
// ---------------------------------------------------------------------------
__global__ __launch_bounds__(64) void wavelet_kernel(const bf16* __restrict__ St,
                                                     const float* __restrict__ Os,
                                                     const int* __restrict__ sel,
                                                     const int* __restrict__ drp,
                                                     float* __restrict__ wout) {
    __shared__ float u[N];
    const int t = threadIdx.x;
    const int l = blockIdx.x;
    const int d = drp[l];
    const ushort* src = (const ushort*)(St + (size_t)d * N);
    for (int j = t; j < N; j += 64) u[j] = us2f(src[j]);
    __syncthreads();
    for (int m = 0; m <= l; m++) {
        float v = 0.0f;
        int wrow = 0;
        if (t < 16) {
            float p[16];
#pragma unroll
            for (int i = 0; i < 16; i++) p[i] = u[sel[m * 16 + i]];
#pragma unroll
            for (int i = 0; i < 16; i++) p[i] *= Os[m * 256 + t * 16 + i];
            const float s0 = (p[0] + p[1]) + (p[2] + p[3]);
            const float s1 = (p[4] + p[5]) + (p[6] + p[7]);
            const float s2 = (p[8] + p[9]) + (p[10] + p[11]);
            const float s3 = (p[12] + p[13]) + (p[14] + p[15]);
            v = (s0 + s1) + (s2 + s3);
            wrow = sel[m * 16 + t];
        }
        __syncthreads();
        if (t < 16) u[wrow] = v;
        __syncthreads();
    }
    float* dst = wout + (size_t)l * N;
    for (int j = t; j < N; j += 64) dst[j] = u[j];
}

// ---------------------------------------------------------------------------
// K8: mask/core. Reads AL16 (bf16). Writes: core rows (fp32, if active),
// masked D (fp32) to out_D, masked D16 (bf16) for the K9 GEMM.
// ---------------------------------------------------------------------------
__global__ __launch_bounds__(256) void maskcore_kernel(const bf16* __restrict__ AL16,
                                                       const int* __restrict__ flags,
                                                       const int* __restrict__ rank,
                                                       float* __restrict__ Dout,
                                                       bf16* __restrict__ D16,
                                                       float* __restrict__ core) {
    const int i = blockIdx.y;
    const int j0 = (blockIdx.x * 256 + threadIdx.x) * 4;
    const int fi = flags[i];
    const int ri = rank[i];
    ushort4 v = *(const ushort4*)((const ushort*)AL16 + (size_t)i * N + j0);
    float4 vf;
    vf.x = us2f(v.x); vf.y = us2f(v.y); vf.z = us2f(v.z); vf.w = us2f(v.w);
    if (fi) *(float4*)(core + (size_t)ri * N + j0) = vf;
    const int4 fj = *(const int4*)(flags + j0);
    bool k0 = (i == j0 + 0) || (fi && fj.x);
    bool k1 = (i == j0 + 1) || (fi && fj.y);
    bool k2 = (i == j0 + 2) || (fi && fj.z);
    bool k3 = (i == j0 + 3) || (fi && fj.w);
    float4 df;
    df.x = k0 ? vf.x : 0.0f; df.y = k1 ? vf.y : 0.0f;
    df.z = k2 ? vf.z : 0.0f; df.w = k3 ? vf.w : 0.0f;
    *(float4*)(Dout + (size_t)i * N + j0) = df;
    ushort4 dv;
    dv.x = k0 ? v.x : (ushort)0; dv.y = k1 ? v.y : (ushort)0;
    dv.z = k2 ? v.z : (ushort)0; dv.w = k3 ? v.w : (ushort)0;
    *(ushort4*)((ushort*)D16 + (size_t)i * N + j0) = dv;
}

// ---------------------------------------------------------------------------
// GEMM v2.2: C[M,N] = Amat @ Bt^T, bf16 in, fp32 acc, bf16/fp32 out.
// 256x256 tile, BK=32, 512 threads (8 waves, 2Mx4N), per-wave 128x64 output.
// T2: XOR granule swizzle phys_slot = logical ^ ((row>>1)&3) -> 2-way = free.
// T3/T4: 4-buffer LDS ring (4 x 32KB = 128KB), 3 tiles in flight, counted
//     s_waitcnt vmcnt(8) once per tile (never 0 in main loop), raw s_barrier.
// T5: s_setprio(1) around each 16-MFMA cluster.
// T1 (new): bijective XCD-rectangle swizzle. Grid 16x16 = 256 blocks, 8 XCDs,
//     32 blocks/XCD arranged as a 4x8 tile-rectangle so consecutive blocks on
//     one XCD share the A-panel in its private L2 (default round-robin
//     replicates every panel into all 8 L2s -> L3 streaming ~1GB/GEMM).
// ---------------------------------------------------------------------------
#define GBM 256
#define GBK 32
#define GNT (N / GBK)

template <bool F32OUT>
__global__ __launch_bounds__(512) void gemm256_kernel(const bf16* __restrict__ Amat,
                                                      const bf16* __restrict__ Bt,
                                                      void* __restrict__ Cv) {
    __shared__ bf16 lds[4][2][GBM * GBK];  // [buf][A/B][256*32] = 128 KB

    const int t = threadIdx.x;
    const int lane = t & 63;
    const int wave = t >> 6;   // 0..7
    const int wm = wave >> 2;  // 0..1
    const int wn = wave & 3;   // 0..3

    // T1: XCD-rectangle swizzle (bijective for 16x16 grid; assumes linear
    // block id round-robins XCDs; wrong assumption => perf-neutral only).
    const int id = blockIdx.y * 16 + blockIdx.x;
    const int xcd = id & 7, slot = id >> 3;
    const int by = ((xcd >> 1) << 2) + (slot >> 3);   // 0..15
    const int bx = ((xcd & 1) << 3) + (slot & 7);     // 0..15
    const int rowBase = by * GBM;
    const int colBase = bx * GBM;

    // staging lane geometry: instruction idx covers rows [idx*16, idx*16+16);
    // lane l: row = idx*16 + (l>>2), physical slot l&3, logical granule
    // (l&3) ^ ((row>>1)&3) = (l&3) ^ ((l>>3)&3). LDS dest linear
    // (wave-uniform base + lane*16).
    const int sr = lane >> 2;
    const int sgo = (((lane & 3) ^ ((lane >> 3) & 3)) << 3);  // element offset of logical granule
    const int w2 = wave * 2;

    // frag-read lane geometry: row = ... + (lane&15), logical granule lane>>4,
    // physical slot = (lane>>4) ^ ((row>>1)&3) = (lane>>4) ^ ((lane>>1)&3).
    const int frow = lane & 15;
    const int fslot = (((lane >> 4) ^ ((lane >> 1) & 3)) << 4);
    const int aoff0 = (wm * 128 + frow) * 64 + fslot;
    const int boff0 = (wn * 64 + frow) * 64 + fslot;

    floatx4 acc[8][4] = {};

#define G_STAGE(bufIdx, opIdx, gbase, rowb, kk0)                                                   \
    do {                                                                                           \
        const bf16* g0_ = (gbase) + (size_t)((rowb) + w2 * 16 + sr) * N + (kk0) + sgo;             \
        const bf16* g1_ = g0_ + 16 * N;                                                            \
        char* l0_ = (char*)&lds[bufIdx][opIdx][0] + w2 * 1024;                                     \
        __builtin_amdgcn_global_load_lds((const __attribute__((address_space(1))) void*)g0_,       \
                                         (__attribute__((address_space(3))) void*)l0_, 16, 0, 0);  \
        __builtin_amdgcn_global_load_lds((const __attribute__((address_space(1))) void*)g1_,       \
                                         (__attribute__((address_space(3))) void*)(l0_ + 1024),    \
                                         16, 0, 0);                                                \
    } while (0)

    // prologue: stage tiles 0,1,2 -> buf 0,1,2 (12 load-instructions/wave)
#pragma unroll
    for (int p = 0; p < 3; p++) {
        G_STAGE(p, 0, Amat, rowBase, p * GBK);
        G_STAGE(p, 1, Bt, colBase, p * GBK);
    }
    asm volatile("s_waitcnt vmcnt(8)" ::: "memory");  // tile 0 landed
    __builtin_amdgcn_s_barrier();

    for (int tt = 0; tt < GNT; tt++) {
        const int buf = tt & 3;
        const char* lA = (const char*)&lds[buf][0][0];
        const char* lB = (const char*)&lds[buf][1][0];
        const int nbuf = (tt + 3) & 3;
        const bool pf = (tt + 3) < GNT;
        const int nk0 = (tt + 3) * GBK;

        // ---- phase 1: stage A(t+3); read af[0..3]+bfv; MFMA mi 0..3 ----
        if (pf) G_STAGE(nbuf, 0, Amat, rowBase, nk0);
        short8 af[4], bfv[4];
#pragma unroll
        for (int mi = 0; mi < 4; mi++) af[mi] = *(const short8*)(lA + aoff0 + mi * 1024);
#pragma unroll
        for (int ni = 0; ni < 4; ni++) bfv[ni] = *(const short8*)(lB + boff0 + ni * 1024);
        __builtin_amdgcn_s_barrier();
        asm volatile("s_waitcnt lgkmcnt(0)" ::: "memory");
        __builtin_amdgcn_s_setprio(1);
#pragma unroll
        for (int mi = 0; mi < 4; mi++)
#pragma unroll
            for (int ni = 0; ni < 4; ni++)
                acc[mi][ni] =
                    __builtin_amdgcn_mfma_f32_16x16x32_bf16(af[mi], bfv[ni], acc[mi][ni], 0, 0, 0);
        __builtin_amdgcn_s_setprio(0);
        __builtin_amdgcn_s_barrier();

        // ---- phase 2: stage B(t+3); read af[4..7]; MFMA mi 4..7 ----
        if (pf) G_STAGE(nbuf, 1, Bt, colBase, nk0);
        short8 ag[4];
#pragma unroll
        for (int mi = 0; mi < 4; mi++) ag[mi] = *(const short8*)(lA + aoff0 + (mi + 4) * 1024);
        __builtin_amdgcn_s_barrier();
        asm volatile("s_waitcnt lgkmcnt(0)" ::: "memory");
        __builtin_amdgcn_s_setprio(1);
#pragma unroll
        for (int mi = 0; mi < 4; mi++)
#pragma unroll
            for (int ni = 0; ni < 4; ni++)
                acc[mi + 4][ni] = __builtin_amdgcn_mfma_f32_16x16x32_bf16(ag[mi], bfv[ni],
                                                                          acc[mi + 4][ni], 0, 0, 0);
        __builtin_amdgcn_s_setprio(0);
        // counted vmcnt: keep tiles t+2, t+3 (8 instr) in flight; t+1 landed.
        asm volatile("s_waitcnt vmcnt(8)" ::: "memory");
        __builtin_amdgcn_s_barrier();
    }
#undef G_STAGE

    const int crow = (lane >> 4) * 4;
    const int ccol = lane & 15;
    const int rb = rowBase + wm * 128;
    const int cb = colBase + wn * 64;
#pragma unroll
    for (int mi = 0; mi < 8; mi++)
#pragma unroll
        for (int ni = 0; ni < 4; ni++)
#pragma unroll
            for (int r = 0; r < 4; r++) {
                const int gr = rb + mi * 16 + crow + r;
                const int gc = cb + ni * 16 + ccol;
                if (F32OUT)
                    ((float*)Cv)[(size_t)gr * N + gc] = acc[mi][ni][r];
                else
                    ((bf16*)Cv)[(size_t)gr * N + gc] = f2bf(acc[mi][ni][r]);
            }
}

// ---------------------------------------------------------------------------
// Dtypes per the reference: A, Os fp32; sel/drp/act/inact int32; outputs fp32.
// Internal compute bf16 MFMA with fp32 accumulate (error << 2% threshold).
//
// Workspace (96 MB): [0,32)MB A16 -> AL16 -> Tt16 (time-shared);
//                    [32,64)MB R16; [64,96)MB Rt16.
// Output-region scratch: St16 in A_rec[0,32MB); D16 in A_rec[32,64MB) bytes
// (both dead before K10 overwrites); flags/rank in wavelets region (dead
// before K6 overwrites).
// ---------------------------------------------------------------------------
extern "C" void kernel_launch(void* const* d_in, const int* in_sizes, int n_in,
                              void* d_out, int out_size, void* d_ws, size_t ws_size,
                              hipStream_t stream) {
    const float* A = (const float*)d_in[0];
    const float* Os = (const float*)d_in[1];
    const int* sel = (const int*)d_in[2];
    const int* drp = (const int*)d_in[3];
    const int* act = (const int*)d_in[4];
    const int* inact = (const int*)d_in[5];

    float* out = (float*)d_out;
    float* out_Arec = out;                          // 4096*4096
    float* out_D    = out + 16777216;               // 4096*4096
    float* out_wav  = out + 33554432;               // 128*4096
    float* out_core = out + 34078720;               // 3968*4096
    float* out_moth = out + 50331648;               // 128*4096
    float* out_fath = out + 50855936;               // 3968*4096

    char* ws = (char*)d_ws;
    const size_t MB = 1024 * 1024;
    bf16* A16  = (bf16*)(ws + 0);             // dead after K5
    bf16* AL16 = (bf16*)(ws + 0);             // written K7, dead after K8
    bf16* Tt16 = (bf16*)(ws + 0);             // written K9, dead after K10
    bf16* R16  = (bf16*)(ws + 32 * MB);
    bf16* Rt16 = (bf16*)(ws + 64 * MB);
    bf16* St16 = (bf16*)out_Arec;                   // A_rec bytes [0,32MB)
    bf16* D16  = (bf16*)(out_Arec + 8388608);       // A_rec bytes [32,64MB)
    int* flags = (int*)out_wav;                     // dead before K6
    int* rank  = flags + N;

    // K1: sequential right-scan -> Rt16 (= R^T, bf16)
    rscan_kernel<<<dim3(N / 4), dim3(64), 0, stream>>>(Os, sel, Rt16);
    // K2: active flags + ranks (scratch in wavelets region)
    prep_kernel<<<dim3(16), dim3(256), 0, stream>>>(act, inact, flags, rank);
    // K3: R16 = transpose(Rt16)
    transcast_kernel<<<dim3(64, 64), dim3(256), 0, stream>>>(Rt16, R16);
    // K4: father/mother rows of R (fp32 out)
    rowgather_kernel<<<dim3(N), dim3(64), 0, stream>>>(R16, flags, rank, out_fath, out_moth);
    // castA: A fp32 -> bf16
    castA_kernel<<<dim3(16384), dim3(256), 0, stream>>>(A, A16);
    // K5: St = R @ A (A symmetric) -> A_rec region scratch
    gemm256_kernel<false><<<dim3(16, 16), dim3(512), 0, stream>>>(R16, A16, St16);
    // K7: A_L = R @ St^T -> ws slot 0 (A16 dead)
    gemm256_kernel<false><<<dim3(16, 16), dim3(512), 0, stream>>>(R16, St16, AL16);
    // K8: core rows (fp32) + masked D (fp32) + masked D16 (bf16)
    maskcore_kernel<<<dim3(4, N), dim3(256), 0, stream>>>(AL16, flags, rank, out_D, D16, out_core);
    // K6: wavelets from St rows (fp32 out; overwrites flags/rank — dead)
    wavelet_kernel<<<dim3(LSTEPS), dim3(64), 0, stream>>>(St16, Os, sel, drp, out_wav);
    // K9: Tt = R^T @ D (D symmetric to bf16 noise) -> ws slot 0 (AL16 dead)
    gemm256_kernel<false><<<dim3(16, 16), dim3(512), 0, stream>>>(Rt16, D16, Tt16);
    // K10: A_rec = Tt @ Rt^T = R^T D R -> fp32 out (St16/D16 scratch dead)
    gemm256_kernel<true><<<dim3(16, 16), dim3(512), 0, stream>>>(Tt16, Rt16, out_Arec);
}

// Round 4
// 782.544 us; speedup vs baseline: 1.6506x; 1.2654x over previous
//
#include <hip/hip_runtime.h>
#include <hip/hip_bf16.h>
#include <stdint.h>

#define N 4096
#define TC 2048
#define LSTEPS 128
#define KSEL 16
#define NACT 3968
#define NIN 128

typedef __hip_bfloat16 bf16;
typedef __attribute__((ext_vector_type(8))) short short8;
typedef __attribute__((ext_vector_type(4))) float floatx4;

static __device__ __forceinline__ bf16 f2bf(float x) { return __float2bfloat16(x); }
static __device__ __forceinline__ float us2f(ushort u) { return __uint_as_float(((unsigned)u) << 16); }
static __device__ __forceinline__ ushort f2us(float x) { return __bfloat16_as_ushort(__float2bfloat16(x)); }

// ---------------------------------------------------------------------------
// prep: active flags + ranks via binary search over the sorted index lists.
// ---------------------------------------------------------------------------
__global__ void prep_kernel(const int* __restrict__ act, const int* __restrict__ inact,
                            int* __restrict__ flags, int* __restrict__ rank) {
    int i = blockIdx.x * blockDim.x + threadIdx.x;
    if (i >= N) return;
    int lo = 0, hi = NACT - 1, f = 0, r = -1;
    while (lo <= hi) {
        int mid = (lo + hi) >> 1, v = act[mid];
        if (v == i) { f = 1; r = mid; break; }
        if (v < i) lo = mid + 1; else hi = mid - 1;
    }
    if (!f) {
        lo = 0; hi = NIN - 1;
        while (lo <= hi) {
            int mid = (lo + hi) >> 1, v = inact[mid];
            if (v == i) { r = mid; break; }
            if (v < i) lo = mid + 1; else hi = mid - 1;
        }
    }
    flags[i] = f;
    rank[i] = r;
}

// ---------------------------------------------------------------------------
// touched: T = union(sel) padded to TC=2048 with untouched indices.
// Outputs: tlist[TC] (compact->global), tpos[N] (global->compact or -1),
// tflag[N] (in-T), selc[2048] (sel remapped to compact space).
// Single block, 1024 threads, LDS scan.
// ---------------------------------------------------------------------------
__global__ __launch_bounds__(1024) void touched_kernel(const int* __restrict__ sel,
                                                       int* __restrict__ tlist,
                                                       int* __restrict__ tpos,
                                                       int* __restrict__ tflag,
                                                       int* __restrict__ selc) {
    __shared__ int flag[N];
    __shared__ int cpos[N];
    __shared__ int wsum[16];
    __shared__ int woff[16];
    __shared__ int s_tau;
    const int t = threadIdx.x;
#pragma unroll
    for (int k = 0; k < 4; k++) flag[t + 1024 * k] = 0;
    __syncthreads();
    flag[sel[t]] = 1;
    flag[sel[t + 1024]] = 1;
    __syncthreads();
    const int b0 = t * 4;
    const int a0 = flag[b0], a1 = flag[b0 + 1], a2 = flag[b0 + 2], a3 = flag[b0 + 3];
    const int s = a0 + a1 + a2 + a3;
    const int lane = t & 63, wv = t >> 6;
    int sc = s;
    for (int off = 1; off < 64; off <<= 1) {
        int o = __shfl_up(sc, off);
        if (lane >= off) sc += o;
    }
    if (lane == 63) wsum[wv] = sc;
    __syncthreads();
    if (t == 0) {
        int acc = 0;
        for (int i = 0; i < 16; i++) { woff[i] = acc; acc += wsum[i]; }
        s_tau = acc;
    }
    __syncthreads();
    const int tau = s_tau;
    const int need = TC - tau;
    int tp = woff[wv] + (sc - s);  // exclusive touched prefix at element b0
    const int aa[4] = {a0, a1, a2, a3};
#pragma unroll
    for (int k = 0; k < 4; k++) {
        const int i = b0 + k;
        int ci;
        if (aa[k]) { ci = tp; tp++; }
        else {
            const int ur = i - tp;  // untouched exclusive rank
            ci = (ur < need) ? (tau + ur) : -1;
        }
        cpos[i] = ci;
        tpos[i] = ci;
        tflag[i] = (ci >= 0) ? 1 : 0;
        if (ci >= 0) tlist[ci] = i;
    }
    __syncthreads();
    selc[t] = cpos[sel[t]];
    selc[t + 1024] = cpos[sel[t + 1024]];
}

// ---------------------------------------------------------------------------
// rscanc: compact right-scan in T-space. Block b owns compact columns
// [4b,4b+4) of R_TT in a 32KB LDS slab; 128 sequential steps. Writes
// Rct = R_TT^T (bf16, coalesced rows).
// ---------------------------------------------------------------------------
__global__ __launch_bounds__(64) void rscanc_kernel(const float* __restrict__ Os,
                                                    const int* __restrict__ selc,
                                                    bf16* __restrict__ Rct) {
    __shared__ float slab[TC * 4];
    const int t = threadIdx.x;
    const int cc = t & 3;
    const int a = t >> 2;
    const int c0 = blockIdx.x * 4;

    for (int r = t; r < TC * 4; r += 64) slab[r] = 0.0f;
    __syncthreads();
    if (t < 4) slab[(c0 + t) * 4 + t] = 1.0f;
    __syncthreads();

    int selr[16];
    float orow[16];
#pragma unroll
    for (int i = 0; i < 16; i++) selr[i] = selc[i];
#pragma unroll
    for (int i = 0; i < 16; i++) orow[i] = Os[a * 16 + i];

    for (int l = 0; l < LSTEPS; l++) {
        float p[16];
#pragma unroll
        for (int i = 0; i < 16; i++) p[i] = slab[selr[i] * 4 + cc];
#pragma unroll
        for (int i = 0; i < 16; i++) p[i] *= orow[i];
        const float s0 = (p[0] + p[1]) + (p[2] + p[3]);
        const float s1 = (p[4] + p[5]) + (p[6] + p[7]);
        const float s2 = (p[8] + p[9]) + (p[10] + p[11]);
        const float s3 = (p[12] + p[13]) + (p[14] + p[15]);
        const float v = (s0 + s1) + (s2 + s3);
        const int wrow = selr[a];
        int seln[16] = {0};
        float orown[16] = {0.f};
        if (l + 1 < LSTEPS) {
#pragma unroll
            for (int i = 0; i < 16; i++) seln[i] = selc[(l + 1) * 16 + i];
#pragma unroll
            for (int i = 0; i < 16; i++) orown[i] = Os[(l + 1) * 256 + a * 16 + i];
        }
        __syncthreads();
        slab[wrow * 4 + cc] = v;
        __syncthreads();
#pragma unroll
        for (int i = 0; i < 16; i++) { selr[i] = seln[i]; orow[i] = orown[i]; }
    }

    for (int ccw = 0; ccw < 4; ccw++) {
        bf16* dst = Rct + (size_t)(c0 + ccw) * TC;
        for (int r = t; r < TC; r += 64) dst[r] = f2bf(slab[r * 4 + ccw]);
    }
}

// ---------------------------------------------------------------------------
// transB: bf16 transpose, src [R x C] -> dst [C x R]. grid (C/64, R/64).
// ---------------------------------------------------------------------------
__global__ __launch_bounds__(256) void transB_kernel(const bf16* __restrict__ src,
                                                     bf16* __restrict__ dst,
                                                     int R, int C) {
    __shared__ ushort tile[64][65];
    const int t = threadIdx.x;
    const int bx = blockIdx.x, by = blockIdx.y;
    const int tr = t >> 4;
    const int tc = (t & 15) * 4;
#pragma unroll
    for (int k = 0; k < 4; k++) {
        int r = tr + 16 * k;
        const ushort* s = (const ushort*)src + (size_t)(by * 64 + r) * C + bx * 64 + tc;
        ushort4 v = *(const ushort4*)s;
        tile[r][tc + 0] = v.x; tile[r][tc + 1] = v.y;
        tile[r][tc + 2] = v.z; tile[r][tc + 3] = v.w;
    }
    __syncthreads();
#pragma unroll
    for (int k = 0; k < 4; k++) {
        int r = tr + 16 * k;
        ushort4 w;
        w.x = tile[tc + 0][r];
        w.y = tile[tc + 1][r];
        w.z = tile[tc + 2][r];
        w.w = tile[tc + 3][r];
        *(ushort4*)((ushort*)dst + (size_t)(bx * 64 + r) * R + by * 64 + tc) = w;
    }
}

// fp32 transpose, src [R x C] -> dst [C x R]. grid (C/64, R/64).
__global__ __launch_bounds__(256) void transF_kernel(const float* __restrict__ src,
                                                     float* __restrict__ dst,
                                                     int R, int C) {
    __shared__ float tile[64][65];
    const int t = threadIdx.x;
    const int bx = blockIdx.x, by = blockIdx.y;
    const int tr = t >> 4;
    const int tc = (t & 15) * 4;
#pragma unroll
    for (int k = 0; k < 4; k++) {
        int r = tr + 16 * k;
        const float* s = src + (size_t)(by * 64 + r) * C + bx * 64 + tc;
        float4 v = *(const float4*)s;
        tile[r][tc + 0] = v.x; tile[r][tc + 1] = v.y;
        tile[r][tc + 2] = v.z; tile[r][tc + 3] = v.w;
    }
    __syncthreads();
#pragma unroll
    for (int k = 0; k < 4; k++) {
        int r = tr + 16 * k;
        float4 w;
        w.x = tile[tc + 0][r];
        w.y = tile[tc + 1][r];
        w.z = tile[tc + 2][r];
        w.w = tile[tc + 3][r];
        *(float4*)(dst + (size_t)(bx * 64 + r) * R + by * 64 + tc) = w;
    }
}

// ---------------------------------------------------------------------------
// gatherAt: At[r,:] = bf16(A[tlist[r],:]). grid (4, TC) x 256.
// ---------------------------------------------------------------------------
__global__ __launch_bounds__(256) void gatherAt_kernel(const float* __restrict__ A,
                                                       const int* __restrict__ tlist,
                                                       bf16* __restrict__ At) {
    const int r = blockIdx.y;
    const int j0 = (blockIdx.x * 256 + threadIdx.x) * 4;
    const float4 v = *(const float4*)(A + (size_t)tlist[r] * N + j0);
    ushort4 o;
    o.x = f2us(v.x); o.y = f2us(v.y); o.z = f2us(v.z); o.w = f2us(v.w);
    *(ushort4*)((ushort*)At + (size_t)r * N + j0) = o;
}

// gatherRowsB: dst[r,:] = src[tlist[r],:], rows of width TC bf16. grid (2, TC).
__global__ __launch_bounds__(256) void gatherRowsB_kernel(const bf16* __restrict__ src,
                                                          const int* __restrict__ tlist,
                                                          bf16* __restrict__ dst) {
    const int r = blockIdx.y;
    const int c0 = (blockIdx.x * 256 + threadIdx.x) * 4;
    ushort4 v = *(const ushort4*)((const ushort*)src + (size_t)tlist[r] * TC + c0);
    *(ushort4*)((ushort*)dst + (size_t)r * TC + c0) = v;
}

// gatherRd128: Rd128[l,:] = Rc[tpos[drp[l]],:]. grid (2, 128).
__global__ __launch_bounds__(256) void gatherRd_kernel(const bf16* __restrict__ Rc,
                                                       const int* __restrict__ tpos,
                                                       const int* __restrict__ drp,
                                                       bf16* __restrict__ Rd) {
    const int l = blockIdx.y;
    const int c0 = (blockIdx.x * 256 + threadIdx.x) * 4;
    const int pr = tpos[drp[l]];
    ushort4 v = *(const ushort4*)((const ushort*)Rc + (size_t)pr * TC + c0);
    *(ushort4*)((ushort*)Rd + (size_t)l * TC + c0) = v;
}

// gatherColsB: Dc[r,c] = Dt[r, tlist[c]]. grid (8, TC) x 256.
__global__ __launch_bounds__(256) void gatherColsB_kernel(const bf16* __restrict__ Dt,
                                                          const int* __restrict__ tlist,
                                                          bf16* __restrict__ Dc) {
    const int r = blockIdx.y;
    const int c = blockIdx.x * 256 + threadIdx.x;
    ((ushort*)Dc)[(size_t)r * TC + c] = ((const ushort*)Dt)[(size_t)r * N + tlist[c]];
}

// assembleY (in place): Y[r,j] = tflag[j] ? C[r,tpos[j]] : Y[r,j]. grid (4, TC).
__global__ __launch_bounds__(256) void assembleY_kernel(bf16* __restrict__ Y,
                                                        const bf16* __restrict__ C,
                                                        const int* __restrict__ tflag,
                                                        const int* __restrict__ tpos) {
    const int r = blockIdx.y;
    const int j0 = (blockIdx.x * 256 + threadIdx.x) * 4;
    ushort4 v = *(const ushort4*)((const ushort*)Y + (size_t)r * N + j0);
    const int4 tf = *(const int4*)(tflag + j0);
    const int4 tp = *(const int4*)(tpos + j0);
    const ushort* crow = (const ushort*)C + (size_t)r * TC;
    if (tf.x) v.x = crow[tp.x];
    if (tf.y) v.y = crow[tp.y];
    if (tf.z) v.z = crow[tp.z];
    if (tf.w) v.w = crow[tp.w];
    *(ushort4*)((ushort*)Y + (size_t)r * N + j0) = v;
}

// ---------------------------------------------------------------------------
// gemmk: C[M,Ncols] = Amat @ Bt^T, bf16 in, fp32 acc. 128x256 tile, BK=32,
// 512 threads (8 waves 2Mx4N), per-wave 64x64 (acc[4][4]). Runtime ld/K.
// T2 swizzle phys16Bslot = logical ^ ((row>>1)&3) (pre-swizzled global src,
// linear LDS dest, swizzled ds_read) -> 2-way banks = free.
// T3/T4: 4-buf ring (96KB), 3 tiles in flight, counted vmcnt(6). T5 setprio.
// grid (Ncols/256, M/128).
// ---------------------------------------------------------------------------
template <bool F32OUT>
__global__ __launch_bounds__(512) void gemmk_kernel(const bf16* __restrict__ Amat, int lda,
                                                    const bf16* __restrict__ Bt, int ldb,
                                                    void* __restrict__ Cv, int ldc, int K) {
    __shared__ bf16 lds[4][(128 + 256) * 32];  // 96 KB

    const int t = threadIdx.x;
    const int lane = t & 63;
    const int wave = t >> 6;
    const int wm = wave >> 2;  // 0..1
    const int wn = wave & 3;   // 0..3
    const int rowBase = blockIdx.y * 128;
    const int colBase = blockIdx.x * 256;

    const int sr = lane >> 2;
    const int sgo = (((lane & 3) ^ ((lane >> 3) & 3)) << 3);

    const int frow = lane & 15;
    const int fslot = (((lane >> 4) ^ ((lane >> 1) & 3)) << 4);
    const int aoff0 = (wm * 64 + frow) * 64 + fslot;
    const int boff0 = 128 * 64 + (wn * 64 + frow) * 64 + fslot;

    floatx4 acc[4][4] = {};

#define GK_STAGE_A(bufIdx, kk0)                                                                    \
    do {                                                                                           \
        const bf16* g_ = Amat + (size_t)(rowBase + wave * 16 + sr) * lda + (kk0) + sgo;            \
        char* l_ = (char*)&lds[bufIdx][0] + wave * 1024;                                           \
        __builtin_amdgcn_global_load_lds((const __attribute__((address_space(1))) void*)g_,        \
                                         (__attribute__((address_space(3))) void*)l_, 16, 0, 0);   \
    } while (0)
#define GK_STAGE_B(bufIdx, kk0)                                                                    \
    do {                                                                                           \
        const bf16* g0_ = Bt + (size_t)(colBase + wave * 32 + sr) * ldb + (kk0) + sgo;             \
        const bf16* g1_ = g0_ + (size_t)16 * ldb;                                                  \
        char* l0_ = (char*)&lds[bufIdx][128 * 32] + wave * 2048;                                   \
        __builtin_amdgcn_global_load_lds((const __attribute__((address_space(1))) void*)g0_,       \
                                         (__attribute__((address_space(3))) void*)l0_, 16, 0, 0);  \
        __builtin_amdgcn_global_load_lds((const __attribute__((address_space(1))) void*)g1_,       \
                                         (__attribute__((address_space(3))) void*)(l0_ + 1024),    \
                                         16, 0, 0);                                                \
    } while (0)

    const int NT = K >> 5;
#pragma unroll
    for (int p = 0; p < 3; p++) {
        GK_STAGE_A(p, p * 32);
        GK_STAGE_B(p, p * 32);
    }
    asm volatile("s_waitcnt vmcnt(6)" ::: "memory");  // tile 0 landed
    __builtin_amdgcn_s_barrier();

    for (int tt = 0; tt < NT; tt++) {
        const int buf = tt & 3;
        const char* lA = (const char*)&lds[buf][0];
        const int nbuf = (tt + 3) & 3;
        const bool pf = (tt + 3) < NT;
        const int nk0 = (tt + 3) * 32;

        // ---- phase 1: stage A(t+3); read af[0..3], bfv[0..1]; MFMA ni 0..1 --
        if (pf) GK_STAGE_A(nbuf, nk0);
        short8 af[4], bfv[4];
#pragma unroll
        for (int mi = 0; mi < 4; mi++) af[mi] = *(const short8*)(lA + aoff0 + mi * 1024);
#pragma unroll
        for (int ni = 0; ni < 2; ni++) bfv[ni] = *(const short8*)(lA + boff0 + ni * 1024);
        __builtin_amdgcn_s_barrier();
        asm volatile("s_waitcnt lgkmcnt(0)" ::: "memory");
        __builtin_amdgcn_s_setprio(1);
#pragma unroll
        for (int mi = 0; mi < 4; mi++)
#pragma unroll
            for (int ni = 0; ni < 2; ni++)
                acc[mi][ni] =
                    __builtin_amdgcn_mfma_f32_16x16x32_bf16(af[mi], bfv[ni], acc[mi][ni], 0, 0, 0);
        __builtin_amdgcn_s_setprio(0);
        __builtin_amdgcn_s_barrier();

        // ---- phase 2: stage B(t+3); read bfv[2..3]; MFMA ni 2..3 ----
        if (pf) GK_STAGE_B(nbuf, nk0);
#pragma unroll
        for (int ni = 2; ni < 4; ni++) bfv[ni] = *(const short8*)(lA + boff0 + ni * 1024);
        __builtin_amdgcn_s_barrier();
        asm volatile("s_waitcnt lgkmcnt(0)" ::: "memory");
        __builtin_amdgcn_s_setprio(1);
#pragma unroll
        for (int mi = 0; mi < 4; mi++)
#pragma unroll
            for (int ni = 2; ni < 4; ni++)
                acc[mi][ni] =
                    __builtin_amdgcn_mfma_f32_16x16x32_bf16(af[mi], bfv[ni], acc[mi][ni], 0, 0, 0);
        __builtin_amdgcn_s_setprio(0);
        // counted vmcnt: keep tiles t+2,t+3 (6 loads) in flight; t+1 landed.
        asm volatile("s_waitcnt vmcnt(6)" ::: "memory");
        __builtin_amdgcn_s_barrier();
    }
#undef GK_STAGE_A
#undef GK_STAGE_B

    const int crow = (lane >> 4) * 4;
    const int ccol = lane & 15;
    const int rb = rowBase + wm * 64;
    const int cb = colBase + wn * 64;
#pragma unroll
    for (int mi = 0; mi < 4; mi++)
#pragma unroll
        for (int ni = 0; ni < 4; ni++)
#pragma unroll
            for (int r = 0; r < 4; r++) {
                const int gr = rb + mi * 16 + crow + r;
                const int gc = cb + ni * 16 + ccol;
                if (F32OUT)
                    ((float*)Cv)[(size_t)gr * ldc + gc] = acc[mi][ni][r];
                else
                    ((bf16*)Cv)[(size_t)gr * ldc + gc] = f2bf(acc[mi][ni][r]);
            }
}

// ---------------------------------------------------------------------------
// maskcore2: A_L row sources: i in T -> Z[tpos[i],:]; else A[i,:] with cols T
// from Zt (A_L symmetric). Writes core rows, D (fp32), Dt = D[T,:] (bf16).
// ---------------------------------------------------------------------------
__global__ __launch_bounds__(256) void maskcore2_kernel(const float* __restrict__ A,
                                                        const bf16* __restrict__ Z,
                                                        const bf16* __restrict__ Zt,
                                                        const int* __restrict__ flags,
                                                        const int* __restrict__ rank,
                                                        const int* __restrict__ tflag,
                                                        const int* __restrict__ tpos,
                                                        float* __restrict__ Dout,
                                                        bf16* __restrict__ Dt,
                                                        float* __restrict__ core) {
    const int i = blockIdx.y;
    const int j0 = (blockIdx.x * 256 + threadIdx.x) * 4;
    const int fi = flags[i];
    const int ri = rank[i];
    const int ti = tflag[i];
    const int pi = tpos[i];
    float4 vf;
    if (ti) {
        const ushort4 v16 = *(const ushort4*)((const ushort*)Z + (size_t)pi * N + j0);
        vf.x = us2f(v16.x); vf.y = us2f(v16.y); vf.z = us2f(v16.z); vf.w = us2f(v16.w);
    } else {
        vf = *(const float4*)(A + (size_t)i * N + j0);
        const int4 tf = *(const int4*)(tflag + j0);
        const int4 tp = *(const int4*)(tpos + j0);
        const ushort* zrow = (const ushort*)Zt + (size_t)i * TC;
        if (tf.x) vf.x = us2f(zrow[tp.x]);
        if (tf.y) vf.y = us2f(zrow[tp.y]);
        if (tf.z) vf.z = us2f(zrow[tp.z]);
        if (tf.w) vf.w = us2f(zrow[tp.w]);
    }
    if (fi) *(float4*)(core + (size_t)ri * N + j0) = vf;
    const int4 fj = *(const int4*)(flags + j0);
    const bool k0 = (i == j0 + 0) || (fi && fj.x);
    const bool k1 = (i == j0 + 1) || (fi && fj.y);
    const bool k2 = (i == j0 + 2) || (fi && fj.z);
    const bool k3 = (i == j0 + 3) || (fi && fj.w);
    float4 df;
    df.x = k0 ? vf.x : 0.0f; df.y = k1 ? vf.y : 0.0f;
    df.z = k2 ? vf.z : 0.0f; df.w = k3 ? vf.w : 0.0f;
    *(float4*)(Dout + (size_t)i * N + j0) = df;
    if (ti) {
        ushort4 dv;
        dv.x = k0 ? f2us(vf.x) : (ushort)0;
        dv.y = k1 ? f2us(vf.y) : (ushort)0;
        dv.z = k2 ? f2us(vf.z) : (ushort)0;
        dv.w = k3 ? f2us(vf.w) : (ushort)0;
        *(ushort4*)((ushort*)Dt + (size_t)pi * N + j0) = dv;
    }
}

// ---------------------------------------------------------------------------
// wavelets: block l: u = Scw[l,:] (= St[drp[l],:]), apply steps 0..l.
// ---------------------------------------------------------------------------
__global__ __launch_bounds__(64) void wavelet_kernel(const bf16* __restrict__ Scw,
                                                     const float* __restrict__ Os,
                                                     const int* __restrict__ sel,
                                                     float* __restrict__ wout) {
    __shared__ float u[N];
    const int t = threadIdx.x;
    const int l = blockIdx.x;
    const ushort* src = (const ushort*)(Scw + (size_t)l * N);
    for (int j = t; j < N; j += 64) u[j] = us2f(src[j]);
    __syncthreads();
    for (int m = 0; m <= l; m++) {
        float v = 0.0f;
        int wrow = 0;
        if (t < 16) {
            float p[16];
#pragma unroll
            for (int i = 0; i < 16; i++) p[i] = u[sel[m * 16 + i]];
#pragma unroll
            for (int i = 0; i < 16; i++) p[i] *= Os[m * 256 + t * 16 + i];
            const float s0 = (p[0] + p[1]) + (p[2] + p[3]);
            const float s1 = (p[4] + p[5]) + (p[6] + p[7]);
            const float s2 = (p[8] + p[9]) + (p[10] + p[11]);
            const float s3 = (p[12] + p[13]) + (p[14] + p[15]);
            v = (s0 + s1) + (s2 + s3);
            wrow = sel[m * 16 + t];
        }
        __syncthreads();
        if (t < 16) u[wrow] = v;
        __syncthreads();
    }
    float* dst = wout + (size_t)l * N;
    for (int j = t; j < N; j += 64) dst[j] = u[j];
}

// ---------------------------------------------------------------------------
// rowgatherR2: father/mother rows of R from compact Rc.
// R[i,j]: i in T -> (j in T ? Rc[tpos[i],tpos[j]] : 0); else delta(i,j).
// ---------------------------------------------------------------------------
__global__ __launch_bounds__(256) void rowgatherR2_kernel(const bf16* __restrict__ Rc,
                                                          const int* __restrict__ flags,
                                                          const int* __restrict__ rank,
                                                          const int* __restrict__ tflag,
                                                          const int* __restrict__ tpos,
                                                          float* __restrict__ father,
                                                          float* __restrict__ mother) {
    const int i = blockIdx.x;
    const int t = threadIdx.x;
    float* dst = flags[i] ? (father + (size_t)rank[i] * N) : (mother + (size_t)rank[i] * N);
    const int ti = tflag[i];
    const ushort* rrow = (const ushort*)Rc + (size_t)(ti ? tpos[i] : 0) * TC;
    for (int it = 0; it < 4; it++) {
        const int j0 = (it * 256 + t) * 4;
        const int4 tf = *(const int4*)(tflag + j0);
        const int4 tp = *(const int4*)(tpos + j0);
        float4 o;
        o.x = tf.x ? (ti ? us2f(rrow[tp.x]) : 0.f) : ((j0 + 0 == i) ? 1.f : 0.f);
        o.y = tf.y ? (ti ? us2f(rrow[tp.y]) : 0.f) : ((j0 + 1 == i) ? 1.f : 0.f);
        o.z = tf.z ? (ti ? us2f(rrow[tp.z]) : 0.f) : ((j0 + 2 == i) ? 1.f : 0.f);
        o.w = tf.w ? (ti ? us2f(rrow[tp.w]) : 0.f) : ((j0 + 3 == i) ? 1.f : 0.f);
        *(float4*)(dst + j0) = o;
    }
}

// ---------------------------------------------------------------------------
// arec: A_rec[i,:] = i in T ? W[tpos[i],:] : (D[i,:] with cols T from Wt).
// (A_rec symmetric.)
// ---------------------------------------------------------------------------
__global__ __launch_bounds__(256) void arec_kernel(const float* __restrict__ W,
                                                   const float* __restrict__ Wt,
                                                   const float* __restrict__ D,
                                                   const int* __restrict__ tflag,
                                                   const int* __restrict__ tpos,
                                                   float* __restrict__ Arec) {
    const int i = blockIdx.y;
    const int j0 = (blockIdx.x * 256 + threadIdx.x) * 4;
    float4 o;
    if (tflag[i]) {
        o = *(const float4*)(W + (size_t)tpos[i] * N + j0);
    } else {
        o = *(const float4*)(D + (size_t)i * N + j0);
        const int4 tf = *(const int4*)(tflag + j0);
        const int4 tp = *(const int4*)(tpos + j0);
        const float* wrow = Wt + (size_t)i * TC;
        if (tf.x) o.x = wrow[tp.x];
        if (tf.y) o.y = wrow[tp.y];
        if (tf.z) o.z = wrow[tp.z];
        if (tf.w) o.w = wrow[tp.w];
    }
    *(float4*)(Arec + (size_t)i * N + j0) = o;
}

// ---------------------------------------------------------------------------
// Compact-T restructure. R = [[R_TT,0],[0,I]] with T = union(sel) padded to
// 2048. All GEMMs in T-space (104 GF total vs 550 GF full):
//   Scw = Rd128 @ At^T rows (wavelet seeds)
//   C2  = Ac Rc^T;  Y = At R^T (assemble);  Z = Rc Y = A_L[T,:]
//   C4  = Dc Rc;    Y2 = Dt R (assemble);   W = Rc^T Y2 = A_rec[T,:]
// Off-T parts are copies; A_L and A_rec symmetric -> off-T rows' T-columns
// come from transposes (Zt, Wt).
//
// ws layout (<=82MB): smalls [0,2)MB; At/Y/Z [2,18); At_T->C2->Zt [18,34);
// Rct [34,42); Rc [42,50); Ac->Y_T->W [50,82); Wt [2,34) after maskcore.
// out_Arec scratch: Dt/Y2 [0,16)MB, Dc [16,24), C4 [24,32), Y2_T [32,48).
// ---------------------------------------------------------------------------
extern "C" void kernel_launch(void* const* d_in, const int* in_sizes, int n_in,
                              void* d_out, int out_size, void* d_ws, size_t ws_size,
                              hipStream_t stream) {
    const float* A = (const float*)d_in[0];
    const float* Os = (const float*)d_in[1];
    const int* sel = (const int*)d_in[2];
    const int* drp = (const int*)d_in[3];
    const int* act = (const int*)d_in[4];
    const int* inact = (const int*)d_in[5];

    float* out = (float*)d_out;
    float* out_Arec = out;                          // 4096*4096
    float* out_D    = out + 16777216;               // 4096*4096
    float* out_wav  = out + 33554432;               // 128*4096
    float* out_core = out + 34078720;               // 3968*4096
    float* out_moth = out + 50331648;               // 128*4096
    float* out_fath = out + 50855936;               // 3968*4096

    char* ws = (char*)d_ws;
    const size_t KB = 1024;
    const size_t MB = 1024 * 1024;
    int* tlist = (int*)(ws + 0);
    int* tpos  = (int*)(ws + 64 * KB);
    int* tflag = (int*)(ws + 128 * KB);
    int* selc  = (int*)(ws + 192 * KB);
    int* flags = (int*)(ws + 256 * KB);
    int* rank  = (int*)(ws + 320 * KB);
    bf16* Rd128 = (bf16*)(ws + 512 * KB);           // 128 x 2048
    bf16* Scw   = (bf16*)(ws + 1 * MB);             // 128 x 4096
    bf16* At    = (bf16*)(ws + 2 * MB);             // 2048 x 4096 -> Y -> Z
    bf16* At_T  = (bf16*)(ws + 18 * MB);            // 4096 x 2048
    bf16* C2    = (bf16*)(ws + 18 * MB);            // 2048 x 2048 (after At_T dead)
    bf16* Zt    = (bf16*)(ws + 18 * MB);            // 4096 x 2048 (after C2 dead)
    bf16* Rct   = (bf16*)(ws + 34 * MB);            // 2048 x 2048
    bf16* Rc    = (bf16*)(ws + 42 * MB);            // 2048 x 2048
    bf16* Ac    = (bf16*)(ws + 50 * MB);            // 2048 x 2048
    bf16* Y_T   = (bf16*)(ws + 50 * MB);            // 4096 x 2048 (after Ac dead)
    float* W    = (float*)(ws + 50 * MB);           // 2048 x 4096 f32 (after Y_T dead)
    float* Wt   = (float*)(ws + 2 * MB);            // 4096 x 2048 f32 (after Z/Zt dead)
    bf16* Y  = At;
    bf16* Z  = At;
    // out_Arec region scratch (dead before arec_kernel):
    bf16* Dt   = (bf16*)out_Arec;                   // 2048 x 4096, bytes [0,16M)
    bf16* Dc   = (bf16*)((char*)out_Arec + 16 * MB);// 2048 x 2048
    bf16* C4   = (bf16*)((char*)out_Arec + 24 * MB);// 2048 x 2048
    bf16* Y2   = Dt;                                 // in place
    bf16* Y2_T = (bf16*)((char*)out_Arec + 32 * MB);// 4096 x 2048

    // 1-2: index prep
    prep_kernel<<<dim3(16), dim3(256), 0, stream>>>(act, inact, flags, rank);
    touched_kernel<<<dim3(1), dim3(1024), 0, stream>>>(sel, tlist, tpos, tflag, selc);
    // 3: At = A[T,:] bf16
    gatherAt_kernel<<<dim3(4, TC), dim3(256), 0, stream>>>(A, tlist, At);
    // 4-5: compact scan -> Rct (= Rc^T), Rc
    rscanc_kernel<<<dim3(TC / 4), dim3(64), 0, stream>>>(Os, selc, Rct);
    transB_kernel<<<dim3(32, 32), dim3(256), 0, stream>>>(Rct, Rc, TC, TC);
    // 6: At_T
    transB_kernel<<<dim3(64, 32), dim3(256), 0, stream>>>(At, At_T, TC, N);
    // 7-8: wavelet seed rows Scw = (Rc rows tpos[drp]) @ At
    gatherRd_kernel<<<dim3(2, 128), dim3(256), 0, stream>>>(Rc, tpos, drp, Rd128);
    gemmk_kernel<false><<<dim3(16, 1), dim3(512), 0, stream>>>(Rd128, TC, At_T, TC, Scw, N, TC);
    // 9-10: Ac = A[T,T] (symmetric => row-gather of At_T); C2 = Ac Rc^T
    gatherRowsB_kernel<<<dim3(2, TC), dim3(256), 0, stream>>>(At_T, tlist, Ac);
    gemmk_kernel<false><<<dim3(8, 16), dim3(512), 0, stream>>>(Ac, TC, Rc, TC, C2, TC, TC);
    // 11-13: Y = At R^T (in place); Z = Rc Y = A_L[T,:]
    assembleY_kernel<<<dim3(4, TC), dim3(256), 0, stream>>>(Y, C2, tflag, tpos);
    transB_kernel<<<dim3(64, 32), dim3(256), 0, stream>>>(Y, Y_T, TC, N);
    gemmk_kernel<false><<<dim3(16, 16), dim3(512), 0, stream>>>(Rc, TC, Y_T, TC, Z, N, TC);
    // 14: Zt for symmetric off-T assembly
    transB_kernel<<<dim3(64, 32), dim3(256), 0, stream>>>(Z, Zt, TC, N);
    // 15: D, core, Dt
    maskcore2_kernel<<<dim3(4, N), dim3(256), 0, stream>>>(A, Z, Zt, flags, rank, tflag, tpos,
                                                          out_D, Dt, out_core);
    // 16-19: Dc = D[T,T]; C4 = Dc Rc; Y2 = Dt R (in place); Y2_T
    gatherColsB_kernel<<<dim3(8, TC), dim3(256), 0, stream>>>(Dt, tlist, Dc);
    gemmk_kernel<false><<<dim3(8, 16), dim3(512), 0, stream>>>(Dc, TC, Rct, TC, C4, TC, TC);
    assembleY_kernel<<<dim3(4, TC), dim3(256), 0, stream>>>(Y2, C4, tflag, tpos);
    transB_kernel<<<dim3(64, 32), dim3(256), 0, stream>>>(Y2, Y2_T, TC, N);
    // 20-21: W = Rc^T Y2 = A_rec[T,:] (fp32); Wt
    gemmk_kernel<true><<<dim3(16, 16), dim3(512), 0, stream>>>(Rct, TC, Y2_T, TC, W, N, TC);
    transF_kernel<<<dim3(64, 32), dim3(256), 0, stream>>>(W, Wt, TC, N);
    // 22-24: independent outputs
    wavelet_kernel<<<dim3(LSTEPS), dim3(64), 0, stream>>>(Scw, Os, sel, out_wav);
    rowgatherR2_kernel<<<dim3(N), dim3(256), 0, stream>>>(Rc, flags, rank, tflag, tpos,
                                                          out_fath, out_moth);
    // 25: final A_rec assembly (out_Arec scratch dead)
    arec_kernel<<<dim3(4, N), dim3(256), 0, stream>>>(W, Wt, out_D, tflag, tpos, out_Arec);
}

// Round 5
// 720.776 us; speedup vs baseline: 1.7921x; 1.0857x over previous
//
#include <hip/hip_runtime.h>
#include <hip/hip_bf16.h>
#include <stdint.h>

#define N 4096
#define TC 2048
#define LSTEPS 128
#define KSEL 16
#define NACT 3968
#define NIN 128

typedef __hip_bfloat16 bf16;
typedef __attribute__((ext_vector_type(8))) short short8;
typedef __attribute__((ext_vector_type(4))) float floatx4;

static __device__ __forceinline__ bf16 f2bf(float x) { return __float2bfloat16(x); }
static __device__ __forceinline__ float us2f(ushort u) { return __uint_as_float(((unsigned)u) << 16); }
static __device__ __forceinline__ ushort f2us(float x) { return __bfloat16_as_ushort(__float2bfloat16(x)); }

// ---------------------------------------------------------------------------
// touched (+ fused prep): T = union(sel) padded to TC with untouched indices.
// Outputs: tlist[TC], tpos[N], tflag[N], selc[2048], dposc[128],
// flags[N]/rank[N] (active-set bookkeeping, fused from old prep kernel).
// ---------------------------------------------------------------------------
__global__ __launch_bounds__(1024) void touched_kernel(const int* __restrict__ sel,
                                                       const int* __restrict__ drp,
                                                       const int* __restrict__ act,
                                                       const int* __restrict__ inact,
                                                       int* __restrict__ tlist,
                                                       int* __restrict__ tpos,
                                                       int* __restrict__ tflag,
                                                       int* __restrict__ selc,
                                                       int* __restrict__ dposc,
                                                       int* __restrict__ flags,
                                                       int* __restrict__ rank) {
    __shared__ int flag[N];
    __shared__ int cpos[N];
    __shared__ int wsum[16];
    __shared__ int woff[16];
    __shared__ int s_tau;
    const int t = threadIdx.x;
#pragma unroll
    for (int k = 0; k < 4; k++) flag[t + 1024 * k] = 0;
    __syncthreads();
    flag[sel[t]] = 1;
    flag[sel[t + 1024]] = 1;
    __syncthreads();
    const int b0 = t * 4;
    const int a0 = flag[b0], a1 = flag[b0 + 1], a2 = flag[b0 + 2], a3 = flag[b0 + 3];
    const int s = a0 + a1 + a2 + a3;
    const int lane = t & 63, wv = t >> 6;
    int sc = s;
    for (int off = 1; off < 64; off <<= 1) {
        int o = __shfl_up(sc, off);
        if (lane >= off) sc += o;
    }
    if (lane == 63) wsum[wv] = sc;
    __syncthreads();
    if (t == 0) {
        int acc = 0;
        for (int i = 0; i < 16; i++) { woff[i] = acc; acc += wsum[i]; }
        s_tau = acc;
    }
    __syncthreads();
    const int tau = s_tau;
    const int need = TC - tau;
    int tp = woff[wv] + (sc - s);
    const int aa[4] = {a0, a1, a2, a3};
#pragma unroll
    for (int k = 0; k < 4; k++) {
        const int i = b0 + k;
        int ci;
        if (aa[k]) { ci = tp; tp++; }
        else {
            const int ur = i - tp;
            ci = (ur < need) ? (tau + ur) : -1;
        }
        cpos[i] = ci;
        tpos[i] = ci;
        tflag[i] = (ci >= 0) ? 1 : 0;
        if (ci >= 0) tlist[ci] = i;
    }
    __syncthreads();
    selc[t] = cpos[sel[t]];
    selc[t + 1024] = cpos[sel[t + 1024]];
    if (t < 128) dposc[t] = cpos[drp[t]];

    // fused prep: flags/rank for 4 indices per thread
#pragma unroll
    for (int k = 0; k < 4; k++) {
        const int i = b0 + k;
        int lo = 0, hi = NACT - 1, f = 0, r = -1;
        while (lo <= hi) {
            int mid = (lo + hi) >> 1, v = act[mid];
            if (v == i) { f = 1; r = mid; break; }
            if (v < i) lo = mid + 1; else hi = mid - 1;
        }
        if (!f) {
            lo = 0; hi = NIN - 1;
            while (lo <= hi) {
                int mid = (lo + hi) >> 1, v = inact[mid];
                if (v == i) { r = mid; break; }
                if (v < i) lo = mid + 1; else hi = mid - 1;
            }
        }
        flags[i] = f;
        rank[i] = r;
    }
}

// ---------------------------------------------------------------------------
// rscanc: compact right-scan in T-space -> Rct = R_TT^T. Also emits
// Rd128[l, c0..c0+3] = Rc[dposc[l], c0..c0+3] from the resident slab.
// ---------------------------------------------------------------------------
__global__ __launch_bounds__(64) void rscanc_kernel(const float* __restrict__ Os,
                                                    const int* __restrict__ selc,
                                                    const int* __restrict__ dposc,
                                                    bf16* __restrict__ Rct,
                                                    bf16* __restrict__ Rd) {
    __shared__ float slab[TC * 4];
    const int t = threadIdx.x;
    const int cc = t & 3;
    const int a = t >> 2;
    const int c0 = blockIdx.x * 4;

    for (int r = t; r < TC * 4; r += 64) slab[r] = 0.0f;
    __syncthreads();
    if (t < 4) slab[(c0 + t) * 4 + t] = 1.0f;
    __syncthreads();

    int selr[16];
    float orow[16];
#pragma unroll
    for (int i = 0; i < 16; i++) selr[i] = selc[i];
#pragma unroll
    for (int i = 0; i < 16; i++) orow[i] = Os[a * 16 + i];

    for (int l = 0; l < LSTEPS; l++) {
        float p[16];
#pragma unroll
        for (int i = 0; i < 16; i++) p[i] = slab[selr[i] * 4 + cc];
#pragma unroll
        for (int i = 0; i < 16; i++) p[i] *= orow[i];
        const float s0 = (p[0] + p[1]) + (p[2] + p[3]);
        const float s1 = (p[4] + p[5]) + (p[6] + p[7]);
        const float s2 = (p[8] + p[9]) + (p[10] + p[11]);
        const float s3 = (p[12] + p[13]) + (p[14] + p[15]);
        const float v = (s0 + s1) + (s2 + s3);
        const int wrow = selr[a];
        int seln[16] = {0};
        float orown[16] = {0.f};
        if (l + 1 < LSTEPS) {
#pragma unroll
            for (int i = 0; i < 16; i++) seln[i] = selc[(l + 1) * 16 + i];
#pragma unroll
            for (int i = 0; i < 16; i++) orown[i] = Os[(l + 1) * 256 + a * 16 + i];
        }
        __syncthreads();
        slab[wrow * 4 + cc] = v;
        __syncthreads();
#pragma unroll
        for (int i = 0; i < 16; i++) { selr[i] = seln[i]; orow[i] = orown[i]; }
    }

    for (int ccw = 0; ccw < 4; ccw++) {
        bf16* dst = Rct + (size_t)(c0 + ccw) * TC;
        for (int r = t; r < TC; r += 64) dst[r] = f2bf(slab[r * 4 + ccw]);
    }
    // Rd128 slice from the resident slab
    for (int l = t; l < LSTEPS; l += 64) {
        const int rrow = dposc[l];
        ushort4 o;
        o.x = f2us(slab[rrow * 4 + 0]);
        o.y = f2us(slab[rrow * 4 + 1]);
        o.z = f2us(slab[rrow * 4 + 2]);
        o.w = f2us(slab[rrow * 4 + 3]);
        *(ushort4*)((ushort*)Rd + (size_t)l * TC + c0) = o;
    }
}

// ---------------------------------------------------------------------------
// transB: bf16 transpose, src [R x C] -> dst [C x R]. grid (C/64, R/64).
// ---------------------------------------------------------------------------
__global__ __launch_bounds__(256) void transB_kernel(const bf16* __restrict__ src,
                                                     bf16* __restrict__ dst,
                                                     int R, int C) {
    __shared__ ushort tile[64][65];
    const int t = threadIdx.x;
    const int bx = blockIdx.x, by = blockIdx.y;
    const int tr = t >> 4;
    const int tc = (t & 15) * 4;
#pragma unroll
    for (int k = 0; k < 4; k++) {
        int r = tr + 16 * k;
        const ushort* s = (const ushort*)src + (size_t)(by * 64 + r) * C + bx * 64 + tc;
        ushort4 v = *(const ushort4*)s;
        tile[r][tc + 0] = v.x; tile[r][tc + 1] = v.y;
        tile[r][tc + 2] = v.z; tile[r][tc + 3] = v.w;
    }
    __syncthreads();
#pragma unroll
    for (int k = 0; k < 4; k++) {
        int r = tr + 16 * k;
        ushort4 w;
        w.x = tile[tc + 0][r];
        w.y = tile[tc + 1][r];
        w.z = tile[tc + 2][r];
        w.w = tile[tc + 3][r];
        *(ushort4*)((ushort*)dst + (size_t)(bx * 64 + r) * R + by * 64 + tc) = w;
    }
}

// fp32 transpose, src [R x C] -> dst [C x R]. grid (C/64, R/64).
__global__ __launch_bounds__(256) void transF_kernel(const float* __restrict__ src,
                                                     float* __restrict__ dst,
                                                     int R, int C) {
    __shared__ float tile[64][65];
    const int t = threadIdx.x;
    const int bx = blockIdx.x, by = blockIdx.y;
    const int tr = t >> 4;
    const int tc = (t & 15) * 4;
#pragma unroll
    for (int k = 0; k < 4; k++) {
        int r = tr + 16 * k;
        const float* s = src + (size_t)(by * 64 + r) * C + bx * 64 + tc;
        float4 v = *(const float4*)s;
        tile[r][tc + 0] = v.x; tile[r][tc + 1] = v.y;
        tile[r][tc + 2] = v.z; tile[r][tc + 3] = v.w;
    }
    __syncthreads();
#pragma unroll
    for (int k = 0; k < 4; k++) {
        int r = tr + 16 * k;
        float4 w;
        w.x = tile[tc + 0][r];
        w.y = tile[tc + 1][r];
        w.z = tile[tc + 2][r];
        w.w = tile[tc + 3][r];
        *(float4*)(dst + (size_t)(bx * 64 + r) * R + by * 64 + tc) = w;
    }
}

// ---------------------------------------------------------------------------
// gatherAtT: AtT[j, p] = bf16(A[j, tlist[p]])  [N x TC]. grid (2, N).
// (tpos compaction is monotone -> reads hit ~every other 4B in a row: ~50%
// sector efficiency, writes fully coalesced.)
// ---------------------------------------------------------------------------
__global__ __launch_bounds__(256) void gatherAtT_kernel(const float* __restrict__ A,
                                                        const int* __restrict__ tlist,
                                                        bf16* __restrict__ AtT) {
    const int j = blockIdx.y;
    const int p0 = (blockIdx.x * 256 + threadIdx.x) * 4;
    const float* arow = A + (size_t)j * N;
    const int4 tl = *(const int4*)(tlist + p0);
    ushort4 o;
    o.x = f2us(arow[tl.x]); o.y = f2us(arow[tl.y]);
    o.z = f2us(arow[tl.z]); o.w = f2us(arow[tl.w]);
    *(ushort4*)((ushort*)AtT + (size_t)j * TC + p0) = o;
}

// gatherRowsB: dst[r,:] = src[tlist[r],:], rows of width TC bf16. grid (2, TC).
__global__ __launch_bounds__(256) void gatherRowsB_kernel(const bf16* __restrict__ src,
                                                          const int* __restrict__ tlist,
                                                          bf16* __restrict__ dst) {
    const int r = blockIdx.y;
    const int c0 = (blockIdx.x * 256 + threadIdx.x) * 4;
    ushort4 v = *(const ushort4*)((const ushort*)src + (size_t)tlist[r] * TC + c0);
    *(ushort4*)((ushort*)dst + (size_t)r * TC + c0) = v;
}

// ---------------------------------------------------------------------------
// gemmk: C[M,Ncols] = Amat @ Bt^T (+ optional row-scatter), bf16 in, fp32 acc.
// 128x256 tile, BK=32, 512 threads (8 waves 2Mx4N), acc[4][4]. 96KB 4-buf
// ring, counted vmcnt(6), T2 swizzle, T5 setprio. grid (Ncols/256, M/128).
// ---------------------------------------------------------------------------
template <bool F32OUT>
__global__ __launch_bounds__(512) void gemmk_kernel(const bf16* __restrict__ Amat, int lda,
                                                    const bf16* __restrict__ Bt, int ldb,
                                                    void* __restrict__ Cv, int ldc, int K,
                                                    const int* __restrict__ rowmap) {
    __shared__ bf16 lds[4][(128 + 256) * 32];  // 96 KB

    const int t = threadIdx.x;
    const int lane = t & 63;
    const int wave = t >> 6;
    const int wm = wave >> 2;  // 0..1
    const int wn = wave & 3;   // 0..3
    const int rowBase = blockIdx.y * 128;
    const int colBase = blockIdx.x * 256;

    const int sr = lane >> 2;
    const int sgo = (((lane & 3) ^ ((lane >> 3) & 3)) << 3);

    const int frow = lane & 15;
    const int fslot = (((lane >> 4) ^ ((lane >> 1) & 3)) << 4);
    const int aoff0 = (wm * 64 + frow) * 64 + fslot;
    const int boff0 = 128 * 64 + (wn * 64 + frow) * 64 + fslot;

    floatx4 acc[4][4] = {};

#define GK_STAGE_A(bufIdx, kk0)                                                                    \
    do {                                                                                           \
        const bf16* g_ = Amat + (size_t)(rowBase + wave * 16 + sr) * lda + (kk0) + sgo;            \
        char* l_ = (char*)&lds[bufIdx][0] + wave * 1024;                                           \
        __builtin_amdgcn_global_load_lds((const __attribute__((address_space(1))) void*)g_,        \
                                         (__attribute__((address_space(3))) void*)l_, 16, 0, 0);   \
    } while (0)
#define GK_STAGE_B(bufIdx, kk0)                                                                    \
    do {                                                                                           \
        const bf16* g0_ = Bt + (size_t)(colBase + wave * 32 + sr) * ldb + (kk0) + sgo;             \
        const bf16* g1_ = g0_ + (size_t)16 * ldb;                                                  \
        char* l0_ = (char*)&lds[bufIdx][128 * 32] + wave * 2048;                                   \
        __builtin_amdgcn_global_load_lds((const __attribute__((address_space(1))) void*)g0_,       \
                                         (__attribute__((address_space(3))) void*)l0_, 16, 0, 0);  \
        __builtin_amdgcn_global_load_lds((const __attribute__((address_space(1))) void*)g1_,       \
                                         (__attribute__((address_space(3))) void*)(l0_ + 1024),    \
                                         16, 0, 0);                                                \
    } while (0)

    const int NT = K >> 5;
#pragma unroll
    for (int p = 0; p < 3; p++) {
        GK_STAGE_A(p, p * 32);
        GK_STAGE_B(p, p * 32);
    }
    asm volatile("s_waitcnt vmcnt(6)" ::: "memory");
    __builtin_amdgcn_s_barrier();

    for (int tt = 0; tt < NT; tt++) {
        const int buf = tt & 3;
        const char* lA = (const char*)&lds[buf][0];
        const int nbuf = (tt + 3) & 3;
        const bool pf = (tt + 3) < NT;
        const int nk0 = (tt + 3) * 32;

        if (pf) GK_STAGE_A(nbuf, nk0);
        short8 af[4], bfv[4];
#pragma unroll
        for (int mi = 0; mi < 4; mi++) af[mi] = *(const short8*)(lA + aoff0 + mi * 1024);
#pragma unroll
        for (int ni = 0; ni < 2; ni++) bfv[ni] = *(const short8*)(lA + boff0 + ni * 1024);
        __builtin_amdgcn_s_barrier();
        asm volatile("s_waitcnt lgkmcnt(0)" ::: "memory");
        __builtin_amdgcn_s_setprio(1);
#pragma unroll
        for (int mi = 0; mi < 4; mi++)
#pragma unroll
            for (int ni = 0; ni < 2; ni++)
                acc[mi][ni] =
                    __builtin_amdgcn_mfma_f32_16x16x32_bf16(af[mi], bfv[ni], acc[mi][ni], 0, 0, 0);
        __builtin_amdgcn_s_setprio(0);
        __builtin_amdgcn_s_barrier();

        if (pf) GK_STAGE_B(nbuf, nk0);
#pragma unroll
        for (int ni = 2; ni < 4; ni++) bfv[ni] = *(const short8*)(lA + boff0 + ni * 1024);
        __builtin_amdgcn_s_barrier();
        asm volatile("s_waitcnt lgkmcnt(0)" ::: "memory");
        __builtin_amdgcn_s_setprio(1);
#pragma unroll
        for (int mi = 0; mi < 4; mi++)
#pragma unroll
            for (int ni = 2; ni < 4; ni++)
                acc[mi][ni] =
                    __builtin_amdgcn_mfma_f32_16x16x32_bf16(af[mi], bfv[ni], acc[mi][ni], 0, 0, 0);
        __builtin_amdgcn_s_setprio(0);
        asm volatile("s_waitcnt vmcnt(6)" ::: "memory");
        __builtin_amdgcn_s_barrier();
    }
#undef GK_STAGE_A
#undef GK_STAGE_B

    const int crow = (lane >> 4) * 4;
    const int ccol = lane & 15;
    const int rb = rowBase + wm * 64;
    const int cb = colBase + wn * 64;
#pragma unroll
    for (int mi = 0; mi < 4; mi++)
#pragma unroll
        for (int ni = 0; ni < 4; ni++)
#pragma unroll
            for (int r = 0; r < 4; r++) {
                const int gr0 = rb + mi * 16 + crow + r;
                const int gr = rowmap ? rowmap[gr0] : gr0;
                const int gc = cb + ni * 16 + ccol;
                if (F32OUT)
                    ((float*)Cv)[(size_t)gr * ldc + gc] = acc[mi][ni][r];
                else
                    ((bf16*)Cv)[(size_t)gr * ldc + gc] = f2bf(acc[mi][ni][r]);
            }
}

// ---------------------------------------------------------------------------
// gemm128: same schedule, 128x128 tile (for TC x TC outputs -> 256 blocks =
// full machine; 64KB ring -> 2 blocks/CU). 8 waves 4Mx2N, acc[2][4].
// Per tile 2 load-instr/wave -> counted vmcnt(4). grid (Ncols/128, M/128).
// ---------------------------------------------------------------------------
template <bool F32OUT>
__global__ __launch_bounds__(512) void gemm128_kernel(const bf16* __restrict__ Amat, int lda,
                                                      const bf16* __restrict__ Bt, int ldb,
                                                      void* __restrict__ Cv, int ldc, int K,
                                                      const int* __restrict__ rowmap) {
    __shared__ bf16 lds[4][(128 + 128) * 32];  // 64 KB

    const int t = threadIdx.x;
    const int lane = t & 63;
    const int wave = t >> 6;
    const int wm = wave >> 1;  // 0..3
    const int wn = wave & 1;   // 0..1
    const int rowBase = blockIdx.y * 128;
    const int colBase = blockIdx.x * 128;

    const int sr = lane >> 2;
    const int sgo = (((lane & 3) ^ ((lane >> 3) & 3)) << 3);

    const int frow = lane & 15;
    const int fslot = (((lane >> 4) ^ ((lane >> 1) & 3)) << 4);
    const int aoff0 = (wm * 32 + frow) * 64 + fslot;
    const int boff0 = 128 * 64 + (wn * 64 + frow) * 64 + fslot;

    floatx4 acc[2][4] = {};

#define G1_STAGE_A(bufIdx, kk0)                                                                    \
    do {                                                                                           \
        const bf16* g_ = Amat + (size_t)(rowBase + wave * 16 + sr) * lda + (kk0) + sgo;            \
        char* l_ = (char*)&lds[bufIdx][0] + wave * 1024;                                           \
        __builtin_amdgcn_global_load_lds((const __attribute__((address_space(1))) void*)g_,        \
                                         (__attribute__((address_space(3))) void*)l_, 16, 0, 0);   \
    } while (0)
#define G1_STAGE_B(bufIdx, kk0)                                                                    \
    do {                                                                                           \
        const bf16* g_ = Bt + (size_t)(colBase + wave * 16 + sr) * ldb + (kk0) + sgo;              \
        char* l_ = (char*)&lds[bufIdx][128 * 32] + wave * 1024;                                    \
        __builtin_amdgcn_global_load_lds((const __attribute__((address_space(1))) void*)g_,        \
                                         (__attribute__((address_space(3))) void*)l_, 16, 0, 0);   \
    } while (0)

    const int NT = K >> 5;
#pragma unroll
    for (int p = 0; p < 3; p++) {
        G1_STAGE_A(p, p * 32);
        G1_STAGE_B(p, p * 32);
    }
    asm volatile("s_waitcnt vmcnt(4)" ::: "memory");
    __builtin_amdgcn_s_barrier();

    for (int tt = 0; tt < NT; tt++) {
        const int buf = tt & 3;
        const char* lA = (const char*)&lds[buf][0];
        const int nbuf = (tt + 3) & 3;
        const bool pf = (tt + 3) < NT;
        const int nk0 = (tt + 3) * 32;

        if (pf) G1_STAGE_A(nbuf, nk0);
        short8 af[2], bfv[4];
#pragma unroll
        for (int mi = 0; mi < 2; mi++) af[mi] = *(const short8*)(lA + aoff0 + mi * 1024);
#pragma unroll
        for (int ni = 0; ni < 2; ni++) bfv[ni] = *(const short8*)(lA + boff0 + ni * 1024);
        __builtin_amdgcn_s_barrier();
        asm volatile("s_waitcnt lgkmcnt(0)" ::: "memory");
        __builtin_amdgcn_s_setprio(1);
#pragma unroll
        for (int mi = 0; mi < 2; mi++)
#pragma unroll
            for (int ni = 0; ni < 2; ni++)
                acc[mi][ni] =
                    __builtin_amdgcn_mfma_f32_16x16x32_bf16(af[mi], bfv[ni], acc[mi][ni], 0, 0, 0);
        __builtin_amdgcn_s_setprio(0);
        __builtin_amdgcn_s_barrier();

        if (pf) G1_STAGE_B(nbuf, nk0);
#pragma unroll
        for (int ni = 2; ni < 4; ni++) bfv[ni] = *(const short8*)(lA + boff0 + ni * 1024);
        __builtin_amdgcn_s_barrier();
        asm volatile("s_waitcnt lgkmcnt(0)" ::: "memory");
        __builtin_amdgcn_s_setprio(1);
#pragma unroll
        for (int mi = 0; mi < 2; mi++)
#pragma unroll
            for (int ni = 2; ni < 4; ni++)
                acc[mi][ni] =
                    __builtin_amdgcn_mfma_f32_16x16x32_bf16(af[mi], bfv[ni], acc[mi][ni], 0, 0, 0);
        __builtin_amdgcn_s_setprio(0);
        asm volatile("s_waitcnt vmcnt(4)" ::: "memory");
        __builtin_amdgcn_s_barrier();
    }
#undef G1_STAGE_A
#undef G1_STAGE_B

    const int crow = (lane >> 4) * 4;
    const int ccol = lane & 15;
    const int rb = rowBase + wm * 32;
    const int cb = colBase + wn * 64;
#pragma unroll
    for (int mi = 0; mi < 2; mi++)
#pragma unroll
        for (int ni = 0; ni < 4; ni++)
#pragma unroll
            for (int r = 0; r < 4; r++) {
                const int gr0 = rb + mi * 16 + crow + r;
                const int gr = rowmap ? rowmap[gr0] : gr0;
                const int gc = cb + ni * 16 + ccol;
                if (F32OUT)
                    ((float*)Cv)[(size_t)gr * ldc + gc] = acc[mi][ni][r];
                else
                    ((bf16*)Cv)[(size_t)gr * ldc + gc] = f2bf(acc[mi][ni][r]);
            }
}

// ---------------------------------------------------------------------------
// maskcore2: A_L rows from Z (i in T) or A+Zt (off-T, symmetric). Writes
// core rows, D (fp32), and Dtc = D[:,T] bf16 [N x TC] (compacted scatter).
// ---------------------------------------------------------------------------
__global__ __launch_bounds__(256) void maskcore2_kernel(const float* __restrict__ A,
                                                        const bf16* __restrict__ Z,
                                                        const bf16* __restrict__ Zt,
                                                        const int* __restrict__ flags,
                                                        const int* __restrict__ rank,
                                                        const int* __restrict__ tflag,
                                                        const int* __restrict__ tpos,
                                                        float* __restrict__ Dout,
                                                        bf16* __restrict__ Dtc,
                                                        float* __restrict__ core) {
    const int i = blockIdx.y;
    const int j0 = (blockIdx.x * 256 + threadIdx.x) * 4;
    const int fi = flags[i];
    const int ri = rank[i];
    const int ti = tflag[i];
    const int pi = tpos[i];
    float4 vf;
    const int4 tf = *(const int4*)(tflag + j0);
    const int4 tp = *(const int4*)(tpos + j0);
    if (ti) {
        const ushort4 v16 = *(const ushort4*)((const ushort*)Z + (size_t)pi * N + j0);
        vf.x = us2f(v16.x); vf.y = us2f(v16.y); vf.z = us2f(v16.z); vf.w = us2f(v16.w);
    } else {
        vf = *(const float4*)(A + (size_t)i * N + j0);
        const ushort* zrow = (const ushort*)Zt + (size_t)i * TC;
        if (tf.x) vf.x = us2f(zrow[tp.x]);
        if (tf.y) vf.y = us2f(zrow[tp.y]);
        if (tf.z) vf.z = us2f(zrow[tp.z]);
        if (tf.w) vf.w = us2f(zrow[tp.w]);
    }
    if (fi) *(float4*)(core + (size_t)ri * N + j0) = vf;
    const int4 fj = *(const int4*)(flags + j0);
    const bool k0 = (i == j0 + 0) || (fi && fj.x);
    const bool k1 = (i == j0 + 1) || (fi && fj.y);
    const bool k2 = (i == j0 + 2) || (fi && fj.z);
    const bool k3 = (i == j0 + 3) || (fi && fj.w);
    float4 df;
    df.x = k0 ? vf.x : 0.0f; df.y = k1 ? vf.y : 0.0f;
    df.z = k2 ? vf.z : 0.0f; df.w = k3 ? vf.w : 0.0f;
    *(float4*)(Dout + (size_t)i * N + j0) = df;
    ushort* drow = (ushort*)Dtc + (size_t)i * TC;
    if (tf.x) drow[tp.x] = f2us(df.x);
    if (tf.y) drow[tp.y] = f2us(df.y);
    if (tf.z) drow[tp.z] = f2us(df.z);
    if (tf.w) drow[tp.w] = f2us(df.w);
}

// ---------------------------------------------------------------------------
// wavelets: block l: u = Scw[l,:], apply steps 0..l (global sel indices).
// ---------------------------------------------------------------------------
__global__ __launch_bounds__(64) void wavelet_kernel(const bf16* __restrict__ Scw,
                                                     const float* __restrict__ Os,
                                                     const int* __restrict__ sel,
                                                     float* __restrict__ wout) {
    __shared__ float u[N];
    const int t = threadIdx.x;
    const int l = blockIdx.x;
    const ushort* src = (const ushort*)(Scw + (size_t)l * N);
    for (int j = t; j < N; j += 64) u[j] = us2f(src[j]);
    __syncthreads();
    for (int m = 0; m <= l; m++) {
        float v = 0.0f;
        int wrow = 0;
        if (t < 16) {
            float p[16];
#pragma unroll
            for (int i = 0; i < 16; i++) p[i] = u[sel[m * 16 + i]];
#pragma unroll
            for (int i = 0; i < 16; i++) p[i] *= Os[m * 256 + t * 16 + i];
            const float s0 = (p[0] + p[1]) + (p[2] + p[3]);
            const float s1 = (p[4] + p[5]) + (p[6] + p[7]);
            const float s2 = (p[8] + p[9]) + (p[10] + p[11]);
            const float s3 = (p[12] + p[13]) + (p[14] + p[15]);
            v = (s0 + s1) + (s2 + s3);
            wrow = sel[m * 16 + t];
        }
        __syncthreads();
        if (t < 16) u[wrow] = v;
        __syncthreads();
    }
    float* dst = wout + (size_t)l * N;
    for (int j = t; j < N; j += 64) dst[j] = u[j];
}

// ---------------------------------------------------------------------------
// rowgatherR2: father/mother rows of R from compact Rc.
// ---------------------------------------------------------------------------
__global__ __launch_bounds__(256) void rowgatherR2_kernel(const bf16* __restrict__ Rc,
                                                          const int* __restrict__ flags,
                                                          const int* __restrict__ rank,
                                                          const int* __restrict__ tflag,
                                                          const int* __restrict__ tpos,
                                                          float* __restrict__ father,
                                                          float* __restrict__ mother) {
    const int i = blockIdx.x;
    const int t = threadIdx.x;
    float* dst = flags[i] ? (father + (size_t)rank[i] * N) : (mother + (size_t)rank[i] * N);
    const int ti = tflag[i];
    const ushort* rrow = (const ushort*)Rc + (size_t)(ti ? tpos[i] : 0) * TC;
    for (int it = 0; it < 4; it++) {
        const int j0 = (it * 256 + t) * 4;
        const int4 tf = *(const int4*)(tflag + j0);
        const int4 tp = *(const int4*)(tpos + j0);
        float4 o;
        o.x = tf.x ? (ti ? us2f(rrow[tp.x]) : 0.f) : ((j0 + 0 == i) ? 1.f : 0.f);
        o.y = tf.y ? (ti ? us2f(rrow[tp.y]) : 0.f) : ((j0 + 1 == i) ? 1.f : 0.f);
        o.z = tf.z ? (ti ? us2f(rrow[tp.z]) : 0.f) : ((j0 + 2 == i) ? 1.f : 0.f);
        o.w = tf.w ? (ti ? us2f(rrow[tp.w]) : 0.f) : ((j0 + 3 == i) ? 1.f : 0.f);
        *(float4*)(dst + j0) = o;
    }
}

// ---------------------------------------------------------------------------
// arec: A_rec[i,:] = i in T ? W[tpos[i],:] : (D[i,:] with cols T from Wt).
// ---------------------------------------------------------------------------
__global__ __launch_bounds__(256) void arec_kernel(const float* __restrict__ W,
                                                   const float* __restrict__ Wt,
                                                   const float* __restrict__ D,
                                                   const int* __restrict__ tflag,
                                                   const int* __restrict__ tpos,
                                                   float* __restrict__ Arec) {
    const int i = blockIdx.y;
    const int j0 = (blockIdx.x * 256 + threadIdx.x) * 4;
    float4 o;
    if (tflag[i]) {
        o = *(const float4*)(W + (size_t)tpos[i] * N + j0);
    } else {
        o = *(const float4*)(D + (size_t)i * N + j0);
        const int4 tf = *(const int4*)(tflag + j0);
        const int4 tp = *(const int4*)(tpos + j0);
        const float* wrow = Wt + (size_t)i * TC;
        if (tf.x) o.x = wrow[tp.x];
        if (tf.y) o.y = wrow[tp.y];
        if (tf.z) o.z = wrow[tp.z];
        if (tf.w) o.w = wrow[tp.w];
    }
    *(float4*)(Arec + (size_t)i * N + j0) = o;
}

// ---------------------------------------------------------------------------
// Consolidated compact-T pipeline (17 launches, was 24):
//   C2t = Rc·Ac  (Ac symmetric; r(X)^T == r(X^T) => numerically identical to
//   old C2 path) row-scattered via tlist into YT -> Y_T in place.
//   C4t = Rct·Dc (Dc symmetric to bf16 noise) row-scattered into Dtc -> Y2_T.
//   Z = Rc·Y_T^T = A_L[T,:];  W = Rc^T·Y2 = A_rec[T,:].
// ws layout (91 MB peak): smalls [0,1); Rd128 [1,1.5); Scw [2,3); Rct [3,11);
//   Rc [11,19); YT [19,35); Ac [35,43); Z [35,51) (Ac dead); Zt [51,67);
//   Dtc [67,83); Dc [83,91); W [19,51) (YT/Z dead); Wt [51,83) (Zt/Dtc dead).
// ---------------------------------------------------------------------------
extern "C" void kernel_launch(void* const* d_in, const int* in_sizes, int n_in,
                              void* d_out, int out_size, void* d_ws, size_t ws_size,
                              hipStream_t stream) {
    const float* A = (const float*)d_in[0];
    const float* Os = (const float*)d_in[1];
    const int* sel = (const int*)d_in[2];
    const int* drp = (const int*)d_in[3];
    const int* act = (const int*)d_in[4];
    const int* inact = (const int*)d_in[5];

    float* out = (float*)d_out;
    float* out_Arec = out;                          // 4096*4096
    float* out_D    = out + 16777216;               // 4096*4096
    float* out_wav  = out + 33554432;               // 128*4096
    float* out_core = out + 34078720;               // 3968*4096
    float* out_moth = out + 50331648;               // 128*4096
    float* out_fath = out + 50855936;               // 3968*4096

    char* ws = (char*)d_ws;
    const size_t KB = 1024;
    const size_t MB = 1024 * 1024;
    int* tlist = (int*)(ws + 0);
    int* tpos  = (int*)(ws + 64 * KB);
    int* tflag = (int*)(ws + 128 * KB);
    int* selc  = (int*)(ws + 192 * KB);
    int* flags = (int*)(ws + 256 * KB);
    int* rank  = (int*)(ws + 320 * KB);
    int* dposc = (int*)(ws + 384 * KB);
    bf16* Rd128 = (bf16*)(ws + 1 * MB);             // 128 x 2048
    bf16* Scw   = (bf16*)(ws + 2 * MB);             // 128 x 4096
    bf16* Rct   = (bf16*)(ws + 3 * MB);             // 2048 x 2048
    bf16* Rc    = (bf16*)(ws + 11 * MB);            // 2048 x 2048
    bf16* YT    = (bf16*)(ws + 19 * MB);            // 4096 x 2048 (At_T -> Y_T)
    bf16* Ac    = (bf16*)(ws + 35 * MB);            // 2048 x 2048 (dead after C2t)
    bf16* Z     = (bf16*)(ws + 35 * MB);            // 2048 x 4096 (over Ac)
    bf16* Zt    = (bf16*)(ws + 51 * MB);            // 4096 x 2048
    bf16* Dtc   = (bf16*)(ws + 67 * MB);            // 4096 x 2048 (D[:,T] -> Y2_T)
    bf16* Dc    = (bf16*)(ws + 83 * MB);            // 2048 x 2048
    float* W    = (float*)(ws + 19 * MB);           // 2048 x 4096 f32 (YT/Z dead)
    float* Wt   = (float*)(ws + 51 * MB);           // 4096 x 2048 f32 (Zt/Dtc dead)

    // 1: indices (touched + fused prep)
    touched_kernel<<<dim3(1), dim3(1024), 0, stream>>>(sel, drp, act, inact, tlist, tpos,
                                                       tflag, selc, dposc, flags, rank);
    // 2: At_T = A[:,T] bf16 (into YT)
    gatherAtT_kernel<<<dim3(2, N), dim3(256), 0, stream>>>(A, tlist, YT);
    // 3: compact scan -> Rct (+ Rd128 slice); 4: Rc
    rscanc_kernel<<<dim3(TC / 4), dim3(64), 0, stream>>>(Os, selc, dposc, Rct, Rd128);
    transB_kernel<<<dim3(32, 32), dim3(256), 0, stream>>>(Rct, Rc, TC, TC);
    // 5-6: wavelet seeds Scw = Rd128 @ At (Bt = At_T) and wavelets
    gemm128_kernel<false><<<dim3(32, 1), dim3(512), 0, stream>>>(Rd128, TC, YT, TC, Scw, N, TC,
                                                                 nullptr);
    wavelet_kernel<<<dim3(LSTEPS), dim3(64), 0, stream>>>(Scw, Os, sel, out_wav);
    // 7-8: Ac = A[T,T]; C2t = Rc·Ac row-scattered into YT (-> Y_T complete)
    gatherRowsB_kernel<<<dim3(2, TC), dim3(256), 0, stream>>>(YT, tlist, Ac);
    gemm128_kernel<false><<<dim3(16, 16), dim3(512), 0, stream>>>(Rc, TC, Ac, TC, YT, TC, TC,
                                                                  tlist);
    // 9-10: Z = Rc @ Y (Bt = Y_T) = A_L[T,:]; Zt
    gemmk_kernel<false><<<dim3(16, 16), dim3(512), 0, stream>>>(Rc, TC, YT, TC, Z, N, TC, nullptr);
    transB_kernel<<<dim3(64, 32), dim3(256), 0, stream>>>(Z, Zt, TC, N);
    // 11: D, core, Dtc = D[:,T]
    maskcore2_kernel<<<dim3(4, N), dim3(256), 0, stream>>>(A, Z, Zt, flags, rank, tflag, tpos,
                                                           out_D, Dtc, out_core);
    // 12-13: Dc = D[T,T]; C4t = Rct·Dc row-scattered into Dtc (-> Y2_T)
    gatherRowsB_kernel<<<dim3(2, TC), dim3(256), 0, stream>>>(Dtc, tlist, Dc);
    gemm128_kernel<false><<<dim3(16, 16), dim3(512), 0, stream>>>(Rct, TC, Dc, TC, Dtc, TC, TC,
                                                                  tlist);
    // 14-15: W = Rc^T @ Y2 (Bt = Y2_T) = A_rec[T,:] fp32; Wt
    gemmk_kernel<true><<<dim3(16, 16), dim3(512), 0, stream>>>(Rct, TC, Dtc, TC, W, N, TC,
                                                               nullptr);
    transF_kernel<<<dim3(64, 32), dim3(256), 0, stream>>>(W, Wt, TC, N);
    // 16: father/mother rows of R
    rowgatherR2_kernel<<<dim3(N), dim3(256), 0, stream>>>(Rc, flags, rank, tflag, tpos,
                                                          out_fath, out_moth);
    // 17: final A_rec assembly
    arec_kernel<<<dim3(4, N), dim3(256), 0, stream>>>(W, Wt, out_D, tflag, tpos, out_Arec);
}

// Round 6
// 705.930 us; speedup vs baseline: 1.8298x; 1.0210x over previous
//
#include <hip/hip_runtime.h>
#include <hip/hip_bf16.h>
#include <stdint.h>

#define N 4096
#define TC 2048
#define LSTEPS 128
#define KSEL 16
#define NACT 3968
#define NIN 128

typedef __hip_bfloat16 bf16;
typedef __attribute__((ext_vector_type(8))) short short8;
typedef __attribute__((ext_vector_type(4))) float floatx4;

static __device__ __forceinline__ bf16 f2bf(float x) { return __float2bfloat16(x); }
static __device__ __forceinline__ float us2f(ushort u) { return __uint_as_float(((unsigned)u) << 16); }
static __device__ __forceinline__ ushort f2us(float x) { return __bfloat16_as_ushort(__float2bfloat16(x)); }

// ---------------------------------------------------------------------------
// touched (+ fused prep): T = union(sel) padded to TC with untouched indices.
// Outputs: tlist[TC], tpos[N], tflag[N], selc[2048], dposc[128], flags/rank,
// zmap[N] (= tflag ? N+tpos : j, B-row indirection for Z/W GEMMs),
// offlist[N-TC] (off-T rows, for the final A_rec patch pass).
// ---------------------------------------------------------------------------
__global__ __launch_bounds__(1024) void touched_kernel(const int* __restrict__ sel,
                                                       const int* __restrict__ drp,
                                                       const int* __restrict__ act,
                                                       const int* __restrict__ inact,
                                                       int* __restrict__ tlist,
                                                       int* __restrict__ tpos,
                                                       int* __restrict__ tflag,
                                                       int* __restrict__ selc,
                                                       int* __restrict__ dposc,
                                                       int* __restrict__ flags,
                                                       int* __restrict__ rank,
                                                       int* __restrict__ zmap,
                                                       int* __restrict__ offlist) {
    __shared__ int flag[N];
    __shared__ int cpos[N];
    __shared__ int wsum[16];
    __shared__ int woff[16];
    __shared__ int s_tau;
    const int t = threadIdx.x;
#pragma unroll
    for (int k = 0; k < 4; k++) flag[t + 1024 * k] = 0;
    __syncthreads();
    flag[sel[t]] = 1;
    flag[sel[t + 1024]] = 1;
    __syncthreads();
    const int b0 = t * 4;
    const int a0 = flag[b0], a1 = flag[b0 + 1], a2 = flag[b0 + 2], a3 = flag[b0 + 3];
    const int s = a0 + a1 + a2 + a3;
    const int lane = t & 63, wv = t >> 6;
    int sc = s;
    for (int off = 1; off < 64; off <<= 1) {
        int o = __shfl_up(sc, off);
        if (lane >= off) sc += o;
    }
    if (lane == 63) wsum[wv] = sc;
    __syncthreads();
    if (t == 0) {
        int acc = 0;
        for (int i = 0; i < 16; i++) { woff[i] = acc; acc += wsum[i]; }
        s_tau = acc;
    }
    __syncthreads();
    const int tau = s_tau;
    const int need = TC - tau;
    int tp = woff[wv] + (sc - s);
    const int aa[4] = {a0, a1, a2, a3};
#pragma unroll
    for (int k = 0; k < 4; k++) {
        const int i = b0 + k;
        int ci;
        if (aa[k]) { ci = tp; tp++; }
        else {
            const int ur = i - tp;
            ci = (ur < need) ? (tau + ur) : -1;
            if (ci < 0) offlist[ur - need] = i;
        }
        cpos[i] = ci;
        tpos[i] = ci;
        tflag[i] = (ci >= 0) ? 1 : 0;
        zmap[i] = (ci >= 0) ? (N + ci) : i;
        if (ci >= 0) tlist[ci] = i;
    }
    __syncthreads();
    selc[t] = cpos[sel[t]];
    selc[t + 1024] = cpos[sel[t + 1024]];
    if (t < 128) dposc[t] = cpos[drp[t]];

#pragma unroll
    for (int k = 0; k < 4; k++) {
        const int i = b0 + k;
        int lo = 0, hi = NACT - 1, f = 0, r = -1;
        while (lo <= hi) {
            int mid = (lo + hi) >> 1, v = act[mid];
            if (v == i) { f = 1; r = mid; break; }
            if (v < i) lo = mid + 1; else hi = mid - 1;
        }
        if (!f) {
            lo = 0; hi = NIN - 1;
            while (lo <= hi) {
                int mid = (lo + hi) >> 1, v = inact[mid];
                if (v == i) { r = mid; break; }
                if (v < i) lo = mid + 1; else hi = mid - 1;
            }
        }
        flags[i] = f;
        rank[i] = r;
    }
}

// ---------------------------------------------------------------------------
// rscanc: compact right-scan in T-space -> Rct = R_TT^T (+ Rd128 slice).
// ---------------------------------------------------------------------------
__global__ __launch_bounds__(64) void rscanc_kernel(const float* __restrict__ Os,
                                                    const int* __restrict__ selc,
                                                    const int* __restrict__ dposc,
                                                    bf16* __restrict__ Rct,
                                                    bf16* __restrict__ Rd) {
    __shared__ float slab[TC * 4];
    const int t = threadIdx.x;
    const int cc = t & 3;
    const int a = t >> 2;
    const int c0 = blockIdx.x * 4;

    for (int r = t; r < TC * 4; r += 64) slab[r] = 0.0f;
    __syncthreads();
    if (t < 4) slab[(c0 + t) * 4 + t] = 1.0f;
    __syncthreads();

    int selr[16];
    float orow[16];
#pragma unroll
    for (int i = 0; i < 16; i++) selr[i] = selc[i];
#pragma unroll
    for (int i = 0; i < 16; i++) orow[i] = Os[a * 16 + i];

    for (int l = 0; l < LSTEPS; l++) {
        float p[16];
#pragma unroll
        for (int i = 0; i < 16; i++) p[i] = slab[selr[i] * 4 + cc];
#pragma unroll
        for (int i = 0; i < 16; i++) p[i] *= orow[i];
        const float s0 = (p[0] + p[1]) + (p[2] + p[3]);
        const float s1 = (p[4] + p[5]) + (p[6] + p[7]);
        const float s2 = (p[8] + p[9]) + (p[10] + p[11]);
        const float s3 = (p[12] + p[13]) + (p[14] + p[15]);
        const float v = (s0 + s1) + (s2 + s3);
        const int wrow = selr[a];
        int seln[16] = {0};
        float orown[16] = {0.f};
        if (l + 1 < LSTEPS) {
#pragma unroll
            for (int i = 0; i < 16; i++) seln[i] = selc[(l + 1) * 16 + i];
#pragma unroll
            for (int i = 0; i < 16; i++) orown[i] = Os[(l + 1) * 256 + a * 16 + i];
        }
        __syncthreads();
        slab[wrow * 4 + cc] = v;
        __syncthreads();
#pragma unroll
        for (int i = 0; i < 16; i++) { selr[i] = seln[i]; orow[i] = orown[i]; }
    }

    for (int ccw = 0; ccw < 4; ccw++) {
        bf16* dst = Rct + (size_t)(c0 + ccw) * TC;
        for (int r = t; r < TC; r += 64) dst[r] = f2bf(slab[r * 4 + ccw]);
    }
    for (int l = t; l < LSTEPS; l += 64) {
        const int rrow = dposc[l];
        ushort4 o;
        o.x = f2us(slab[rrow * 4 + 0]);
        o.y = f2us(slab[rrow * 4 + 1]);
        o.z = f2us(slab[rrow * 4 + 2]);
        o.w = f2us(slab[rrow * 4 + 3]);
        *(ushort4*)((ushort*)Rd + (size_t)l * TC + c0) = o;
    }
}

// ---------------------------------------------------------------------------
// transB: bf16 transpose, src [R x C] -> dst [C x R]. grid (C/64, R/64).
// ---------------------------------------------------------------------------
__global__ __launch_bounds__(256) void transB_kernel(const bf16* __restrict__ src,
                                                     bf16* __restrict__ dst,
                                                     int R, int C) {
    __shared__ ushort tile[64][65];
    const int t = threadIdx.x;
    const int bx = blockIdx.x, by = blockIdx.y;
    const int tr = t >> 4;
    const int tc = (t & 15) * 4;
#pragma unroll
    for (int k = 0; k < 4; k++) {
        int r = tr + 16 * k;
        const ushort* s = (const ushort*)src + (size_t)(by * 64 + r) * C + bx * 64 + tc;
        ushort4 v = *(const ushort4*)s;
        tile[r][tc + 0] = v.x; tile[r][tc + 1] = v.y;
        tile[r][tc + 2] = v.z; tile[r][tc + 3] = v.w;
    }
    __syncthreads();
#pragma unroll
    for (int k = 0; k < 4; k++) {
        int r = tr + 16 * k;
        ushort4 w;
        w.x = tile[tc + 0][r];
        w.y = tile[tc + 1][r];
        w.z = tile[tc + 2][r];
        w.w = tile[tc + 3][r];
        *(ushort4*)((ushort*)dst + (size_t)(bx * 64 + r) * R + by * 64 + tc) = w;
    }
}

// ---------------------------------------------------------------------------
// gatherAtT: AtT[j, p] = bf16(A[j, tlist[p]])  [N x TC]. grid (2, N).
// ---------------------------------------------------------------------------
__global__ __launch_bounds__(256) void gatherAtT_kernel(const float* __restrict__ A,
                                                        const int* __restrict__ tlist,
                                                        bf16* __restrict__ AtT) {
    const int j = blockIdx.y;
    const int p0 = (blockIdx.x * 256 + threadIdx.x) * 4;
    const float* arow = A + (size_t)j * N;
    const int4 tl = *(const int4*)(tlist + p0);
    ushort4 o;
    o.x = f2us(arow[tl.x]); o.y = f2us(arow[tl.y]);
    o.z = f2us(arow[tl.z]); o.w = f2us(arow[tl.w]);
    *(ushort4*)((ushort*)AtT + (size_t)j * TC + p0) = o;
}

// ---------------------------------------------------------------------------
// gemmk: C[M,Ncols] = Amat @ Bt^T, bf16 in, fp32 acc. 128x256 tile, BK=32,
// 512 threads, acc[4][4], 96KB 4-buf ring, counted vmcnt(6), swizzle, setprio.
// Options: bmap (B-row indirection, hoisted to 2 loads), rowmap (C-row
// scatter), Tt/ldt (transposed co-write: Tt[gc*ldt+compact_row], lanes
// {l,l+16,l+32,l+48} tile consecutive rows -> line-coalesced).
// grid (Ncols/256, M/128).
// ---------------------------------------------------------------------------
template <bool F32OUT>
__global__ __launch_bounds__(512) void gemmk_kernel(const bf16* __restrict__ Amat, int lda,
                                                    const bf16* __restrict__ Bt, int ldb,
                                                    void* __restrict__ Cv, int ldc, int K,
                                                    const int* __restrict__ rowmap,
                                                    const int* __restrict__ bmap,
                                                    void* __restrict__ Tt, int ldt) {
    __shared__ bf16 lds[4][(128 + 256) * 32];  // 96 KB

    const int t = threadIdx.x;
    const int lane = t & 63;
    const int wave = t >> 6;
    const int wm = wave >> 2;  // 0..1
    const int wn = wave & 3;   // 0..3
    const int rowBase = blockIdx.y * 128;
    const int colBase = blockIdx.x * 256;

    const int sr = lane >> 2;
    const int sgo = (((lane & 3) ^ ((lane >> 3) & 3)) << 3);

    const int bR = colBase + wave * 32 + sr;
    const int bIdx0 = bmap ? bmap[bR] : bR;
    const int bIdx1 = bmap ? bmap[bR + 16] : (bR + 16);

    const int frow = lane & 15;
    const int fslot = (((lane >> 4) ^ ((lane >> 1) & 3)) << 4);
    const int aoff0 = (wm * 64 + frow) * 64 + fslot;
    const int boff0 = 128 * 64 + (wn * 64 + frow) * 64 + fslot;

    floatx4 acc[4][4] = {};

#define GK_STAGE_A(bufIdx, kk0)                                                                    \
    do {                                                                                           \
        const bf16* g_ = Amat + (size_t)(rowBase + wave * 16 + sr) * lda + (kk0) + sgo;            \
        char* l_ = (char*)&lds[bufIdx][0] + wave * 1024;                                           \
        __builtin_amdgcn_global_load_lds((const __attribute__((address_space(1))) void*)g_,        \
                                         (__attribute__((address_space(3))) void*)l_, 16, 0, 0);   \
    } while (0)
#define GK_STAGE_B(bufIdx, kk0)                                                                    \
    do {                                                                                           \
        const bf16* g0_ = Bt + (size_t)bIdx0 * ldb + (kk0) + sgo;                                  \
        const bf16* g1_ = Bt + (size_t)bIdx1 * ldb + (kk0) + sgo;                                  \
        char* l0_ = (char*)&lds[bufIdx][128 * 32] + wave * 2048;                                   \
        __builtin_amdgcn_global_load_lds((const __attribute__((address_space(1))) void*)g0_,       \
                                         (__attribute__((address_space(3))) void*)l0_, 16, 0, 0);  \
        __builtin_amdgcn_global_load_lds((const __attribute__((address_space(1))) void*)g1_,       \
                                         (__attribute__((address_space(3))) void*)(l0_ + 1024),    \
                                         16, 0, 0);                                                \
    } while (0)

    const int NT = K >> 5;
#pragma unroll
    for (int p = 0; p < 3; p++) {
        GK_STAGE_A(p, p * 32);
        GK_STAGE_B(p, p * 32);
    }
    asm volatile("s_waitcnt vmcnt(6)" ::: "memory");
    __builtin_amdgcn_s_barrier();

    for (int tt = 0; tt < NT; tt++) {
        const int buf = tt & 3;
        const char* lA = (const char*)&lds[buf][0];
        const int nbuf = (tt + 3) & 3;
        const bool pf = (tt + 3) < NT;
        const int nk0 = (tt + 3) * 32;

        if (pf) GK_STAGE_A(nbuf, nk0);
        short8 af[4], bfv[4];
#pragma unroll
        for (int mi = 0; mi < 4; mi++) af[mi] = *(const short8*)(lA + aoff0 + mi * 1024);
#pragma unroll
        for (int ni = 0; ni < 2; ni++) bfv[ni] = *(const short8*)(lA + boff0 + ni * 1024);
        __builtin_amdgcn_s_barrier();
        asm volatile("s_waitcnt lgkmcnt(0)" ::: "memory");
        __builtin_amdgcn_s_setprio(1);
#pragma unroll
        for (int mi = 0; mi < 4; mi++)
#pragma unroll
            for (int ni = 0; ni < 2; ni++)
                acc[mi][ni] =
                    __builtin_amdgcn_mfma_f32_16x16x32_bf16(af[mi], bfv[ni], acc[mi][ni], 0, 0, 0);
        __builtin_amdgcn_s_setprio(0);
        __builtin_amdgcn_s_barrier();

        if (pf) GK_STAGE_B(nbuf, nk0);
#pragma unroll
        for (int ni = 2; ni < 4; ni++) bfv[ni] = *(const short8*)(lA + boff0 + ni * 1024);
        __builtin_amdgcn_s_barrier();
        asm volatile("s_waitcnt lgkmcnt(0)" ::: "memory");
        __builtin_amdgcn_s_setprio(1);
#pragma unroll
        for (int mi = 0; mi < 4; mi++)
#pragma unroll
            for (int ni = 2; ni < 4; ni++)
                acc[mi][ni] =
                    __builtin_amdgcn_mfma_f32_16x16x32_bf16(af[mi], bfv[ni], acc[mi][ni], 0, 0, 0);
        __builtin_amdgcn_s_setprio(0);
        asm volatile("s_waitcnt vmcnt(6)" ::: "memory");
        __builtin_amdgcn_s_barrier();
    }
#undef GK_STAGE_A
#undef GK_STAGE_B

    const int crow = (lane >> 4) * 4;
    const int ccol = lane & 15;
    const int rbc = rowBase + wm * 64;
    const int cb = colBase + wn * 64;
#pragma unroll
    for (int mi = 0; mi < 4; mi++)
#pragma unroll
        for (int ni = 0; ni < 4; ni++) {
            const int grc = rbc + mi * 16 + crow;
            const int gc = cb + ni * 16 + ccol;
#pragma unroll
            for (int r = 0; r < 4; r++) {
                const int gr = rowmap ? rowmap[grc + r] : (grc + r);
                if (F32OUT)
                    ((float*)Cv)[(size_t)gr * ldc + gc] = acc[mi][ni][r];
                else
                    ((bf16*)Cv)[(size_t)gr * ldc + gc] = f2bf(acc[mi][ni][r]);
            }
            if (Tt) {
                if (F32OUT) {
                    float4 w;
                    w.x = acc[mi][ni][0]; w.y = acc[mi][ni][1];
                    w.z = acc[mi][ni][2]; w.w = acc[mi][ni][3];
                    *(float4*)((float*)Tt + (size_t)gc * ldt + grc) = w;
                } else {
                    ushort4 w;
                    w.x = f2us(acc[mi][ni][0]); w.y = f2us(acc[mi][ni][1]);
                    w.z = f2us(acc[mi][ni][2]); w.w = f2us(acc[mi][ni][3]);
                    *(ushort4*)((ushort*)Tt + (size_t)gc * ldt + grc) = w;
                }
            }
        }
}

// ---------------------------------------------------------------------------
// gemm128: 128x128 tile variant (full-machine grids on TCxTC outputs).
// 8 waves 4Mx2N, acc[2][4], 64KB ring, vmcnt(4). Optional bmap.
// grid (Ncols/128, M/128).
// ---------------------------------------------------------------------------
template <bool F32OUT>
__global__ __launch_bounds__(512) void gemm128_kernel(const bf16* __restrict__ Amat, int lda,
                                                      const bf16* __restrict__ Bt, int ldb,
                                                      void* __restrict__ Cv, int ldc, int K,
                                                      const int* __restrict__ bmap) {
    __shared__ bf16 lds[4][(128 + 128) * 32];  // 64 KB

    const int t = threadIdx.x;
    const int lane = t & 63;
    const int wave = t >> 6;
    const int wm = wave >> 1;  // 0..3
    const int wn = wave & 1;   // 0..1
    const int rowBase = blockIdx.y * 128;
    const int colBase = blockIdx.x * 128;

    const int sr = lane >> 2;
    const int sgo = (((lane & 3) ^ ((lane >> 3) & 3)) << 3);

    const int bR = colBase + wave * 16 + sr;
    const int bIdx = bmap ? bmap[bR] : bR;

    const int frow = lane & 15;
    const int fslot = (((lane >> 4) ^ ((lane >> 1) & 3)) << 4);
    const int aoff0 = (wm * 32 + frow) * 64 + fslot;
    const int boff0 = 128 * 64 + (wn * 64 + frow) * 64 + fslot;

    floatx4 acc[2][4] = {};

#define G1_STAGE_A(bufIdx, kk0)                                                                    \
    do {                                                                                           \
        const bf16* g_ = Amat + (size_t)(rowBase + wave * 16 + sr) * lda + (kk0) + sgo;            \
        char* l_ = (char*)&lds[bufIdx][0] + wave * 1024;                                           \
        __builtin_amdgcn_global_load_lds((const __attribute__((address_space(1))) void*)g_,        \
                                         (__attribute__((address_space(3))) void*)l_, 16, 0, 0);   \
    } while (0)
#define G1_STAGE_B(bufIdx, kk0)                                                                    \
    do {                                                                                           \
        const bf16* g_ = Bt + (size_t)bIdx * ldb + (kk0) + sgo;                                    \
        char* l_ = (char*)&lds[bufIdx][128 * 32] + wave * 1024;                                    \
        __builtin_amdgcn_global_load_lds((const __attribute__((address_space(1))) void*)g_,        \
                                         (__attribute__((address_space(3))) void*)l_, 16, 0, 0);   \
    } while (0)

    const int NT = K >> 5;
#pragma unroll
    for (int p = 0; p < 3; p++) {
        G1_STAGE_A(p, p * 32);
        G1_STAGE_B(p, p * 32);
    }
    asm volatile("s_waitcnt vmcnt(4)" ::: "memory");
    __builtin_amdgcn_s_barrier();

    for (int tt = 0; tt < NT; tt++) {
        const int buf = tt & 3;
        const char* lA = (const char*)&lds[buf][0];
        const int nbuf = (tt + 3) & 3;
        const bool pf = (tt + 3) < NT;
        const int nk0 = (tt + 3) * 32;

        if (pf) G1_STAGE_A(nbuf, nk0);
        short8 af[2], bfv[4];
#pragma unroll
        for (int mi = 0; mi < 2; mi++) af[mi] = *(const short8*)(lA + aoff0 + mi * 1024);
#pragma unroll
        for (int ni = 0; ni < 2; ni++) bfv[ni] = *(const short8*)(lA + boff0 + ni * 1024);
        __builtin_amdgcn_s_barrier();
        asm volatile("s_waitcnt lgkmcnt(0)" ::: "memory");
        __builtin_amdgcn_s_setprio(1);
#pragma unroll
        for (int mi = 0; mi < 2; mi++)
#pragma unroll
            for (int ni = 0; ni < 2; ni++)
                acc[mi][ni] =
                    __builtin_amdgcn_mfma_f32_16x16x32_bf16(af[mi], bfv[ni], acc[mi][ni], 0, 0, 0);
        __builtin_amdgcn_s_setprio(0);
        __builtin_amdgcn_s_barrier();

        if (pf) G1_STAGE_B(nbuf, nk0);
#pragma unroll
        for (int ni = 2; ni < 4; ni++) bfv[ni] = *(const short8*)(lA + boff0 + ni * 1024);
        __builtin_amdgcn_s_barrier();
        asm volatile("s_waitcnt lgkmcnt(0)" ::: "memory");
        __builtin_amdgcn_s_setprio(1);
#pragma unroll
        for (int mi = 0; mi < 2; mi++)
#pragma unroll
            for (int ni = 2; ni < 4; ni++)
                acc[mi][ni] =
                    __builtin_amdgcn_mfma_f32_16x16x32_bf16(af[mi], bfv[ni], acc[mi][ni], 0, 0, 0);
        __builtin_amdgcn_s_setprio(0);
        asm volatile("s_waitcnt vmcnt(4)" ::: "memory");
        __builtin_amdgcn_s_barrier();
    }
#undef G1_STAGE_A
#undef G1_STAGE_B

    const int crow = (lane >> 4) * 4;
    const int ccol = lane & 15;
    const int rb = rowBase + wm * 32;
    const int cb = colBase + wn * 64;
#pragma unroll
    for (int mi = 0; mi < 2; mi++)
#pragma unroll
        for (int ni = 0; ni < 4; ni++)
#pragma unroll
            for (int r = 0; r < 4; r++) {
                const int gr = rb + mi * 16 + crow + r;
                const int gc = cb + ni * 16 + ccol;
                if (F32OUT)
                    ((float*)Cv)[(size_t)gr * ldc + gc] = acc[mi][ni][r];
                else
                    ((bf16*)Cv)[(size_t)gr * ldc + gc] = f2bf(acc[mi][ni][r]);
            }
}

// ---------------------------------------------------------------------------
// maskcore2: A_L rows from Z (i in T) or A+Zt (off-T, symmetric). Writes
// core rows, D (fp32), and Dtc = D[:,T] bf16 [N x TC].
// ---------------------------------------------------------------------------
__global__ __launch_bounds__(256) void maskcore2_kernel(const float* __restrict__ A,
                                                        const bf16* __restrict__ Z,
                                                        const bf16* __restrict__ Zt,
                                                        const int* __restrict__ flags,
                                                        const int* __restrict__ rank,
                                                        const int* __restrict__ tflag,
                                                        const int* __restrict__ tpos,
                                                        float* __restrict__ Dout,
                                                        bf16* __restrict__ Dtc,
                                                        float* __restrict__ core) {
    const int i = blockIdx.y;
    const int j0 = (blockIdx.x * 256 + threadIdx.x) * 4;
    const int fi = flags[i];
    const int ri = rank[i];
    const int ti = tflag[i];
    const int pi = tpos[i];
    float4 vf;
    const int4 tf = *(const int4*)(tflag + j0);
    const int4 tp = *(const int4*)(tpos + j0);
    if (ti) {
        const ushort4 v16 = *(const ushort4*)((const ushort*)Z + (size_t)pi * N + j0);
        vf.x = us2f(v16.x); vf.y = us2f(v16.y); vf.z = us2f(v16.z); vf.w = us2f(v16.w);
    } else {
        vf = *(const float4*)(A + (size_t)i * N + j0);
        const ushort* zrow = (const ushort*)Zt + (size_t)i * TC;
        if (tf.x) vf.x = us2f(zrow[tp.x]);
        if (tf.y) vf.y = us2f(zrow[tp.y]);
        if (tf.z) vf.z = us2f(zrow[tp.z]);
        if (tf.w) vf.w = us2f(zrow[tp.w]);
    }
    if (fi) *(float4*)(core + (size_t)ri * N + j0) = vf;
    const int4 fj = *(const int4*)(flags + j0);
    const bool k0 = (i == j0 + 0) || (fi && fj.x);
    const bool k1 = (i == j0 + 1) || (fi && fj.y);
    const bool k2 = (i == j0 + 2) || (fi && fj.z);
    const bool k3 = (i == j0 + 3) || (fi && fj.w);
    float4 df;
    df.x = k0 ? vf.x : 0.0f; df.y = k1 ? vf.y : 0.0f;
    df.z = k2 ? vf.z : 0.0f; df.w = k3 ? vf.w : 0.0f;
    *(float4*)(Dout + (size_t)i * N + j0) = df;
    ushort* drow = (ushort*)Dtc + (size_t)i * TC;
    if (tf.x) drow[tp.x] = f2us(df.x);
    if (tf.y) drow[tp.y] = f2us(df.y);
    if (tf.z) drow[tp.z] = f2us(df.z);
    if (tf.w) drow[tp.w] = f2us(df.w);
}

// ---------------------------------------------------------------------------
// wavelets (wave-parallel): all 64 lanes; 4 lanes per output row, float4
// Os/sel loads, 2-level shfl_xor reduce.
// ---------------------------------------------------------------------------
__global__ __launch_bounds__(64) void wavelet_kernel(const bf16* __restrict__ Scw,
                                                     const float* __restrict__ Os,
                                                     const int* __restrict__ sel,
                                                     float* __restrict__ wout) {
    __shared__ float u[N];
    const int t = threadIdx.x;
    const int l = blockIdx.x;
    const int a = t >> 2, q = t & 3;
    const ushort* src = (const ushort*)(Scw + (size_t)l * N);
    for (int j = t; j < N; j += 64) u[j] = us2f(src[j]);
    __syncthreads();
    for (int m = 0; m <= l; m++) {
        const int4 si = *(const int4*)(sel + m * 16 + q * 4);
        const float4 ov = *(const float4*)(Os + m * 256 + a * 16 + q * 4);
        float pp = ov.x * u[si.x] + ov.y * u[si.y] + ov.z * u[si.z] + ov.w * u[si.w];
        pp += __shfl_xor(pp, 1);
        pp += __shfl_xor(pp, 2);
        const int wrow = sel[m * 16 + a];
        __syncthreads();
        if (q == 0) u[wrow] = pp;
        __syncthreads();
    }
    float* dst = wout + (size_t)l * N;
    for (int j = t; j < N; j += 64) dst[j] = u[j];
}

// ---------------------------------------------------------------------------
// rowgatherR2: father/mother rows of R from compact Rc.
// ---------------------------------------------------------------------------
__global__ __launch_bounds__(256) void rowgatherR2_kernel(const bf16* __restrict__ Rc,
                                                          const int* __restrict__ flags,
                                                          const int* __restrict__ rank,
                                                          const int* __restrict__ tflag,
                                                          const int* __restrict__ tpos,
                                                          float* __restrict__ father,
                                                          float* __restrict__ mother) {
    const int i = blockIdx.x;
    const int t = threadIdx.x;
    float* dst = flags[i] ? (father + (size_t)rank[i] * N) : (mother + (size_t)rank[i] * N);
    const int ti = tflag[i];
    const ushort* rrow = (const ushort*)Rc + (size_t)(ti ? tpos[i] : 0) * TC;
    for (int it = 0; it < 4; it++) {
        const int j0 = (it * 256 + t) * 4;
        const int4 tf = *(const int4*)(tflag + j0);
        const int4 tp = *(const int4*)(tpos + j0);
        float4 o;
        o.x = tf.x ? (ti ? us2f(rrow[tp.x]) : 0.f) : ((j0 + 0 == i) ? 1.f : 0.f);
        o.y = tf.y ? (ti ? us2f(rrow[tp.y]) : 0.f) : ((j0 + 1 == i) ? 1.f : 0.f);
        o.z = tf.z ? (ti ? us2f(rrow[tp.z]) : 0.f) : ((j0 + 2 == i) ? 1.f : 0.f);
        o.w = tf.w ? (ti ? us2f(rrow[tp.w]) : 0.f) : ((j0 + 3 == i) ? 1.f : 0.f);
        *(float4*)(dst + j0) = o;
    }
}

// ---------------------------------------------------------------------------
// arecoff: off-T rows of A_rec: D row with T-cols patched from Wt.
// (T rows were row-scattered directly by the W GEMM.) grid (4, N-TC).
// ---------------------------------------------------------------------------
__global__ __launch_bounds__(256) void arecoff_kernel(const float* __restrict__ D,
                                                      const float* __restrict__ Wt,
                                                      const int* __restrict__ offlist,
                                                      const int* __restrict__ tflag,
                                                      const int* __restrict__ tpos,
                                                      float* __restrict__ Arec) {
    const int i = offlist[blockIdx.y];
    const int j0 = (blockIdx.x * 256 + threadIdx.x) * 4;
    float4 o = *(const float4*)(D + (size_t)i * N + j0);
    const int4 tf = *(const int4*)(tflag + j0);
    const int4 tp = *(const int4*)(tpos + j0);
    const float* wrow = Wt + (size_t)i * TC;
    if (tf.x) o.x = wrow[tp.x];
    if (tf.y) o.y = wrow[tp.y];
    if (tf.z) o.z = wrow[tp.z];
    if (tf.w) o.w = wrow[tp.w];
    *(float4*)(Arec + (size_t)i * N + j0) = o;
}

// ---------------------------------------------------------------------------
// Compact-T pipeline v3 (13 launches):
//   bmap folds Ac/Dc gathers into the C2t/C4t GEMM B-stage (hoisted, free).
//   zmap[j] = tflag ? N+tpos : j lets Z/W GEMMs read the patched Y rows from
//   the [At_T|Yc] / [Dtc|D4c] stacked regions without materializing Y.
//   Z GEMM co-writes Zt; W GEMM row-scatters into out_Arec AND co-writes Wt;
//   arecoff patches only off-T rows.
// ws: smalls [0,1); Rd128 [1,2); Scw [2,3); Rct [3,11); Rc [11,19);
//   B-region [19,43) = At_T[NxTC]+Yc[TCxTC] -> Dtc+D4c (At_T dead after Z);
//   Z [43,59); Zt [59,75) -> Wt f32 [43,75) (Z/Zt dead after maskcore2).
// ---------------------------------------------------------------------------
extern "C" void kernel_launch(void* const* d_in, const int* in_sizes, int n_in,
                              void* d_out, int out_size, void* d_ws, size_t ws_size,
                              hipStream_t stream) {
    const float* A = (const float*)d_in[0];
    const float* Os = (const float*)d_in[1];
    const int* sel = (const int*)d_in[2];
    const int* drp = (const int*)d_in[3];
    const int* act = (const int*)d_in[4];
    const int* inact = (const int*)d_in[5];

    float* out = (float*)d_out;
    float* out_Arec = out;                          // 4096*4096
    float* out_D    = out + 16777216;               // 4096*4096
    float* out_wav  = out + 33554432;               // 128*4096
    float* out_core = out + 34078720;               // 3968*4096
    float* out_moth = out + 50331648;               // 128*4096
    float* out_fath = out + 50855936;               // 3968*4096

    char* ws = (char*)d_ws;
    const size_t KB = 1024;
    const size_t MB = 1024 * 1024;
    int* tlist   = (int*)(ws + 0);
    int* tpos    = (int*)(ws + 64 * KB);
    int* tflag   = (int*)(ws + 128 * KB);
    int* selc    = (int*)(ws + 192 * KB);
    int* flags   = (int*)(ws + 256 * KB);
    int* rank    = (int*)(ws + 320 * KB);
    int* dposc   = (int*)(ws + 384 * KB);
    int* zmap    = (int*)(ws + 448 * KB);
    int* offlist = (int*)(ws + 512 * KB);
    bf16* Rd128 = (bf16*)(ws + 1 * MB);             // 128 x 2048
    bf16* Scw   = (bf16*)(ws + 2 * MB);             // 128 x 4096
    bf16* Rct   = (bf16*)(ws + 3 * MB);             // 2048 x 2048
    bf16* Rc    = (bf16*)(ws + 11 * MB);            // 2048 x 2048
    bf16* Breg  = (bf16*)(ws + 19 * MB);            // [N+TC] x TC stacked region
    bf16* Yc    = Breg + (size_t)N * TC;            // rows N..N+TC-1
    bf16* Z     = (bf16*)(ws + 43 * MB);            // 2048 x 4096
    bf16* Zt    = (bf16*)(ws + 59 * MB);            // 4096 x 2048
    float* Wt   = (float*)(ws + 43 * MB);           // 4096 x 2048 f32 (Z/Zt dead)

    // 1: indices
    touched_kernel<<<dim3(1), dim3(1024), 0, stream>>>(sel, drp, act, inact, tlist, tpos, tflag,
                                                       selc, dposc, flags, rank, zmap, offlist);
    // 2: At_T = A[:,T] bf16 (rows 0..N-1 of B-region)
    gatherAtT_kernel<<<dim3(2, N), dim3(256), 0, stream>>>(A, tlist, Breg);
    // 3-4: compact scan -> Rct (+ Rd128); Rc
    rscanc_kernel<<<dim3(TC / 4), dim3(64), 0, stream>>>(Os, selc, dposc, Rct, Rd128);
    transB_kernel<<<dim3(32, 32), dim3(256), 0, stream>>>(Rct, Rc, TC, TC);
    // 5-6: wavelet seeds Scw = Rd128 @ At; wavelets
    gemm128_kernel<false><<<dim3(32, 1), dim3(512), 0, stream>>>(Rd128, TC, Breg, TC, Scw, N, TC,
                                                                 nullptr);
    wavelet_kernel<<<dim3(LSTEPS), dim3(64), 0, stream>>>(Scw, Os, sel, out_wav);
    // 7: C2t = Rc @ A[T,T]^T via bmap=tlist -> Yc (rows N.. of B-region)
    gemm128_kernel<false><<<dim3(16, 16), dim3(512), 0, stream>>>(Rc, TC, Breg, TC, Yc, TC, TC,
                                                                  tlist);
    // 8: Z = Rc @ Y^T via bmap=zmap = A_L[T,:]; co-write Zt
    gemmk_kernel<false><<<dim3(16, 16), dim3(512), 0, stream>>>(Rc, TC, Breg, TC, Z, N, TC,
                                                                nullptr, zmap, Zt, TC);
    // 9: D, core, Dtc (over At_T region, dead)
    maskcore2_kernel<<<dim3(4, N), dim3(256), 0, stream>>>(A, Z, Zt, flags, rank, tflag, tpos,
                                                           out_D, Breg, out_core);
    // 10: C4t = Rct @ D[T,T]^T via bmap=tlist -> D4c (rows N.. of B-region)
    gemm128_kernel<false><<<dim3(16, 16), dim3(512), 0, stream>>>(Rct, TC, Breg, TC, Yc, TC, TC,
                                                                  tlist);
    // 11: W = Rct @ Y2^T via bmap=zmap = A_rec[T,:]; row-scatter into
    //     out_Arec (rows tlist) + co-write Wt (Z/Zt dead)
    gemmk_kernel<true><<<dim3(16, 16), dim3(512), 0, stream>>>(Rct, TC, Breg, TC, out_Arec, N, TC,
                                                               tlist, zmap, Wt, TC);
    // 12: off-T rows of A_rec
    arecoff_kernel<<<dim3(4, N - TC), dim3(256), 0, stream>>>(out_D, Wt, offlist, tflag, tpos,
                                                              out_Arec);
    // 13: father/mother rows of R
    rowgatherR2_kernel<<<dim3(N), dim3(256), 0, stream>>>(Rc, flags, rank, tflag, tpos,
                                                          out_fath, out_moth);
}